// Round 6
// baseline (486.179 us; speedup 1.0000x reference)
//
#include <hip/hip_runtime.h>

#define RADIUS 3
#define C_CH 128
#define N_FR 16
#define H0 120
#define W0 160
#define HW0 (H0*W0)
#define H1 30
#define W1 40
#define EXT 10
#define NCELL 100
#define M_PT 1536
#define FM1SZ (N_FR*H1*W1*C_CH)     // fm1T floats
#define FTSZ  ((size_t)N_FR*C_CH*HW0) // fmapT floats (157.3 MB)
#define GT_SZ (M_PT*9*C_CH)         // gmapT floats
#define SCSTR 12                    // sC dword stride per cell
#define SSTR 36                     // staged-window dword stride per cell (144B: 16B-aligned, bank-tiling)
#define NBKT 256

// ---- fused transpose + pool: fm0 [N,C,120,160] -> fmapT [N,120,160,C] + fm1T [N,30,40,C] ----
__global__ __launch_bounds__(256) void transpose_pool(const float* __restrict__ fm0,
                                                      float* __restrict__ fmapT,
                                                      float* __restrict__ fm1T) {
    __shared__ float s[16 * 4 * 161];   // [c16][y4][x161]
    int blk = blockIdx.x;               // n*30 + yo
    int yo = blk % H1;
    int n = blk / H1;
    int y0 = yo * 4;
    int tid = threadIdx.x;
    for (int cc = 0; cc < C_CH; cc += 16) {
        for (int idx = tid; idx < 16 * 4 * W0; idx += 256) {
            int c = idx / (4 * W0);
            int rem = idx - c * (4 * W0);
            int yl = rem / W0;
            int x = rem - yl * W0;
            s[(c * 4 + yl) * 161 + x] =
                fm0[(((size_t)(n * C_CH + cc + c)) * H0 + y0 + yl) * W0 + x];
        }
        __syncthreads();
        for (int idx = tid; idx < 4 * W0 * 16; idx += 256) {
            int yl = idx / (W0 * 16);
            int rem = idx - yl * (W0 * 16);
            int x = rem >> 4;
            int c = rem & 15;
            fmapT[(((size_t)n * H0 + y0 + yl) * W0 + x) * C_CH + cc + c] =
                s[(c * 4 + yl) * 161 + x];
        }
        for (int idx = tid; idx < W1 * 16; idx += 256) {
            int xo = idx >> 4;
            int c = idx & 15;
            float sum = 0.f;
#pragma unroll
            for (int yl = 0; yl < 4; ++yl)
#pragma unroll
                for (int dx = 0; dx < 4; ++dx)
                    sum += s[(c * 4 + yl) * 161 + xo * 4 + dx];
            fm1T[(((size_t)n * H1 + yo) * W1 + xo) * C_CH + cc + c] = sum * (1.f / 16.f);
        }
        __syncthreads();
    }
}

// ---- fallback planar pool + transpose (used when ws can't hold fmapT) ----
__global__ __launch_bounds__(256) void pool_kernel(const float* __restrict__ fm0,
                                                   float* __restrict__ tmp) {
    int idx = blockIdx.x * blockDim.x + threadIdx.x;
    int total = N_FR * C_CH * H1 * W1;
    if (idx >= total) return;
    int x = idx % W1;
    int y = (idx / W1) % H1;
    int nc = idx / (W1 * H1);
    const float* src = fm0 + ((size_t)nc * H0 + y * 4) * W0 + x * 4;
    float sm = 0.f;
#pragma unroll
    for (int dy = 0; dy < 4; ++dy) {
        float4 v = *reinterpret_cast<const float4*>(src + dy * W0);
        sm += v.x + v.y + v.z + v.w;
    }
    tmp[idx] = sm * (1.f / 16.f);
}

__global__ __launch_bounds__(256) void fm1_transpose(const float* __restrict__ src,
                                                     float* __restrict__ dst) {
    __shared__ float s[C_CH * 41];
    int b = blockIdx.x;            // n*H1 + y
    int y = b % H1;
    int n = b / H1;
    for (int t = threadIdx.x; t < C_CH * W1; t += 256) {
        int c = t / W1, x = t - c * W1;
        s[c * 41 + x] = src[((size_t)(n * C_CH + c) * H1 + y) * W1 + x];
    }
    __syncthreads();
    float* dp = dst + (size_t)b * W1 * C_CH;
    for (int t = threadIdx.x; t < W1 * C_CH; t += 256) {
        int x = t >> 7, c = t & 127;
        dp[(size_t)x * C_CH + c] = s[c * 41 + x];
    }
}

// ---- gmap [M][C][9] -> gmapT [M][9][C] ----
__global__ __launch_bounds__(128) void gtrans_kernel(const float* __restrict__ g,
                                                     float* __restrict__ gT) {
    int m = blockIdx.x;
    const float* src = g + (size_t)m * (C_CH * 9);
    float* dst = gT + (size_t)m * (C_CH * 9);
    for (int o = threadIdx.x; o < C_CH * 9; o += 128) {
        int c = o & (C_CH - 1);
        int pq = o >> 7;
        dst[o] = src[c * 9 + pq];
    }
}

// ---- (frame, y-band) bucket sort ----
__device__ __forceinline__ int sort_key(const int* jj, const float* coords, int e) {
    float cy = coords[(size_t)e * 18 + 1];
    int by0 = (int)floorf(cy) - RADIUS;
    int band = min(max(by0 >> 3, 0), 15);
    return jj[e] * 16 + band;
}

__global__ void zero_kernel(int* cnt) {
    int t = blockIdx.x * blockDim.x + threadIdx.x;
    if (t < 2 * NBKT) cnt[t] = 0;
}

__global__ void hist_kernel(const int* __restrict__ jj, const float* __restrict__ coords,
                            int* __restrict__ cnt, int E) {
    __shared__ int h[NBKT];
    int tid = threadIdx.x;
    h[tid] = 0;
    __syncthreads();
    int e = blockIdx.x * blockDim.x + tid;
    if (e < E) atomicAdd(&h[sort_key(jj, coords, e)], 1);
    __syncthreads();
    if (h[tid] > 0) atomicAdd(&cnt[tid], h[tid]);
}

__global__ void scan_kernel(const int* __restrict__ cnt, int* __restrict__ off) {
    if (threadIdx.x == 0) {
        int s = 0;
        for (int f = 0; f < NBKT; ++f) { off[f] = s; s += cnt[f]; }
    }
}

__global__ void scatter_kernel(const int* __restrict__ jj, const float* __restrict__ coords,
                               int* __restrict__ off, int* __restrict__ perm, int E) {
    __shared__ int h[NBKT];
    __shared__ int base[NBKT];
    int tid = threadIdx.x;
    h[tid] = 0;
    __syncthreads();
    int e = blockIdx.x * blockDim.x + tid;
    int k = 0, rank = 0;
    if (e < E) {
        k = sort_key(jj, coords, e);
        rank = atomicAdd(&h[k], 1);
    }
    __syncthreads();
    if (h[tid] > 0) base[tid] = atomicAdd(&off[tid], h[tid]);
    __syncthreads();
    if (e < E) perm[base[k] + rank] = e;
}

// ---- new corr: chunked LDS staging, thread = union-window cell ----
__global__ __launch_bounds__(128) void corr_new(
        const float* __restrict__ fmap,   // [N,C,H0,W0] planar (used if fmapT null)
        const float* __restrict__ fmapT,  // [N,H0,W0,C] or null
        const float* __restrict__ fm1T,   // [N,H1,W1,C]
        const float* __restrict__ gmapT,  // [M,9,C]
        const float* __restrict__ coords,
        const int* __restrict__ ii,
        const int* __restrict__ jj,
        const int* __restrict__ perm,
        float* __restrict__ out) {
    __shared__ float smem[2 * NCELL * SSTR];   // sfm0 | sfm1 ; sC aliases front
    float* sfm0 = smem;
    float* sfm1 = smem + NCELL * SSTR;

    int e = perm ? perm[blockIdx.x] : (int)blockIdx.x;
    int tid = threadIdx.x;

    int iie = __builtin_amdgcn_readfirstlane(ii[e]);
    int jje = __builtin_amdgcn_readfirstlane(jj[e]);
    const float* cb = coords + (size_t)e * 18;

    float cx = cb[0], cy = cb[1];
    int bx0 = (int)floorf(cx) - RADIUS;
    int by0 = (int)floorf(cy) - RADIUS;
    int bx1 = (int)floorf(cx * 0.25f) - RADIUS;
    int by1 = (int)floorf(cy * 0.25f) - RADIUS;

    int cell = min(tid, NCELL - 1);
    const float* gp = gmapT + (size_t)iie * (9 * C_CH);
    const float* f1base = fm1T + (size_t)jje * H1 * W1 * C_CH;

    float acc0[9], acc1[9];
#pragma unroll
    for (int pq = 0; pq < 9; ++pq) { acc0[pq] = 0.f; acc1[pq] = 0.f; }

    for (int cc = 0; cc < C_CH; cc += 32) {
        // stage level-1 window (channel-last): 8 lanes/cell, 128B contiguous per cell
        for (int idx = tid; idx < NCELL * 8; idx += 128) {
            int cl = idx >> 3, pk = idx & 7;
            int iy = cl / EXT, ix = cl - iy * EXT;
            int gy = min(max(by1 + iy, 0), H1 - 1);
            int gx = min(max(bx1 + ix, 0), W1 - 1);
            float4 v = *reinterpret_cast<const float4*>(
                f1base + ((size_t)gy * W1 + gx) * C_CH + cc + pk * 4);
            *reinterpret_cast<float4*>(&sfm1[cl * SSTR + pk * 4]) = v;
        }
        if (fmapT) {
            const float* f0base = fmapT + (size_t)jje * HW0 * C_CH;
            for (int idx = tid; idx < NCELL * 8; idx += 128) {
                int cl = idx >> 3, pk = idx & 7;
                int iy = cl / EXT, ix = cl - iy * EXT;
                int gy = min(max(by0 + iy, 0), H0 - 1);
                int gx = min(max(bx0 + ix, 0), W0 - 1);
                float4 v = *reinterpret_cast<const float4*>(
                    f0base + ((size_t)gy * W0 + gx) * C_CH + cc + pk * 4);
                *reinterpret_cast<float4*>(&sfm0[cl * SSTR + pk * 4]) = v;
            }
        } else {
            // planar staging: (c, row, col16) — rows read contiguously
            const float* fb = fmap + ((size_t)jje * C_CH + cc) * HW0;
            for (int idx = tid; idx < 32 * EXT * 16; idx += 128) {
                int c = idx / (EXT * 16);
                int rem = idx - c * (EXT * 16);
                int row = rem >> 4;
                int col = rem & 15;
                int gy = min(max(by0 + row, 0), H0 - 1);
                int gx = min(max(bx0 + col, 0), W0 - 1);
                float v = fb[(size_t)c * HW0 + gy * W0 + gx];
                if (col < EXT) sfm0[(row * EXT + col) * SSTR + c] = v;
            }
        }
        __syncthreads();
#pragma unroll
        for (int k = 0; k < 8; ++k) {
            float4 f0 = *reinterpret_cast<const float4*>(&sfm0[cell * SSTR + k * 4]);
            float4 f1 = *reinterpret_cast<const float4*>(&sfm1[cell * SSTR + k * 4]);
#pragma unroll
            for (int pq = 0; pq < 9; ++pq) {
                float4 g4 = *reinterpret_cast<const float4*>(gp + pq * C_CH + cc + k * 4);
                acc0[pq] += f0.x * g4.x + f0.y * g4.y + f0.z * g4.z + f0.w * g4.w;
                acc1[pq] += f1.x * g4.x + f1.y * g4.y + f1.z * g4.z + f1.w * g4.w;
            }
        }
        __syncthreads();
    }

    float* sC = smem;   // alias (all sfm reads done)
    if (tid < NCELL) {
        float* s0 = &sC[cell * SCSTR];
        float* s1 = &sC[NCELL * SCSTR + cell * SCSTR];
        *reinterpret_cast<float4*>(s0)     = float4{acc0[0], acc0[1], acc0[2], acc0[3]};
        *reinterpret_cast<float4*>(s0 + 4) = float4{acc0[4], acc0[5], acc0[6], acc0[7]};
        s0[8] = acc0[8];
        *reinterpret_cast<float4*>(s1)     = float4{acc1[0], acc1[1], acc1[2], acc1[3]};
        *reinterpret_cast<float4*>(s1 + 4) = float4{acc1[4], acc1[5], acc1[6], acc1[7]};
        s1[8] = acc1[8];
    }
    __syncthreads();

    for (int o = tid; o < 882; o += 128) {
        int lvl = o & 1;
        int r = o >> 1;
        int pq = r % 9;
        int ab = r / 9;
        int a = ab / 7, b = ab - a * 7;
        float s = lvl ? 0.25f : 1.f;
        float x = cb[pq * 2 + 0] * s;
        float y = cb[pq * 2 + 1] * s;
        float x0f = floorf(x), y0f = floorf(y);
        float fx = x - x0f, fy = y - y0f;
        int offx = (int)x0f - RADIUS - (lvl ? bx1 : bx0);
        int offy = (int)y0f - RADIUS - (lvl ? by1 : by0);
        int cell2 = (offy + a) * EXT + (offx + b);
        int base = lvl * (NCELL * SCSTR) + cell2 * SCSTR + pq;
        float c00 = sC[base];
        float c01 = sC[base + SCSTR];
        float c10 = sC[base + EXT * SCSTR];
        float c11 = sC[base + EXT * SCSTR + SCSTR];
        float v = (1.f - fy) * (1.f - fx) * c00 + (1.f - fy) * fx * c01
                + fy * (1.f - fx) * c10 + fy * fx * c11;
        out[(size_t)e * 882 + (size_t)r * 2 + lvl] = v;
    }
}

// ---- old corr (R5) kept as small-ws fallback ----
__global__ __launch_bounds__(128) void corr_old(
        const float* __restrict__ fmap, const float* __restrict__ fm1T,
        const float* __restrict__ gmap, const float* __restrict__ coords,
        const int* __restrict__ ii, const int* __restrict__ jj,
        const int* __restrict__ perm, float* __restrict__ out) {
    __shared__ float sC[2 * NCELL * SCSTR];
    int e = perm ? perm[blockIdx.x] : (int)blockIdx.x;
    int tid = threadIdx.x;
    int iie = __builtin_amdgcn_readfirstlane(ii[e]);
    int jje = __builtin_amdgcn_readfirstlane(jj[e]);
    const float* cb = coords + (size_t)e * 18;
    float cx = cb[0], cy = cb[1];
    int bx0 = (int)floorf(cx) - RADIUS;
    int by0 = (int)floorf(cy) - RADIUS;
    int bx1 = (int)floorf(cx * 0.25f) - RADIUS;
    int by1 = (int)floorf(cy * 0.25f) - RADIUS;
    int cell = min(tid, NCELL - 1);
    int iy = cell / EXT, ix = cell - iy * EXT;
    int gy0 = min(max(by0 + iy, 0), H0 - 1);
    int gx0 = min(max(bx0 + ix, 0), W0 - 1);
    int gy1 = min(max(by1 + iy, 0), H1 - 1);
    int gx1 = min(max(bx1 + ix, 0), W1 - 1);
    const float* fp0 = fmap + (size_t)jje * C_CH * HW0 + gy0 * W0 + gx0;
    const float* fp1 = fm1T + (((size_t)jje * H1 + gy1) * W1 + gx1) * C_CH;
    float acc0[9], acc1[9];
#pragma unroll
    for (int pq = 0; pq < 9; ++pq) { acc0[pq] = 0.f; acc1[pq] = 0.f; }
    const float* gpr = gmap + (size_t)iie * (C_CH * 9);
#pragma unroll 2
    for (int c = 0; c < C_CH; c += 4) {
        float f0 = fp0[(size_t)(c + 0) * HW0];
        float f1 = fp0[(size_t)(c + 1) * HW0];
        float f2 = fp0[(size_t)(c + 2) * HW0];
        float f3 = fp0[(size_t)(c + 3) * HW0];
        float4 fv = *reinterpret_cast<const float4*>(fp1 + c);
#pragma unroll
        for (int pq = 0; pq < 9; ++pq) {
            float g0 = gpr[(c + 0) * 9 + pq];
            float g1 = gpr[(c + 1) * 9 + pq];
            float g2 = gpr[(c + 2) * 9 + pq];
            float g3 = gpr[(c + 3) * 9 + pq];
            acc0[pq] += f0 * g0 + f1 * g1 + f2 * g2 + f3 * g3;
            acc1[pq] += fv.x * g0 + fv.y * g1 + fv.z * g2 + fv.w * g3;
        }
    }
    if (tid < NCELL) {
        float* s0 = &sC[cell * SCSTR];
        float* s1 = &sC[NCELL * SCSTR + cell * SCSTR];
        *reinterpret_cast<float4*>(s0)     = float4{acc0[0], acc0[1], acc0[2], acc0[3]};
        *reinterpret_cast<float4*>(s0 + 4) = float4{acc0[4], acc0[5], acc0[6], acc0[7]};
        s0[8] = acc0[8];
        *reinterpret_cast<float4*>(s1)     = float4{acc1[0], acc1[1], acc1[2], acc1[3]};
        *reinterpret_cast<float4*>(s1 + 4) = float4{acc1[4], acc1[5], acc1[6], acc1[7]};
        s1[8] = acc1[8];
    }
    __syncthreads();
    for (int o = tid; o < 882; o += 128) {
        int lvl = o & 1;
        int r = o >> 1;
        int pq = r % 9;
        int ab = r / 9;
        int a = ab / 7, b = ab - a * 7;
        float s = lvl ? 0.25f : 1.f;
        float x = cb[pq * 2 + 0] * s;
        float y = cb[pq * 2 + 1] * s;
        float x0f = floorf(x), y0f = floorf(y);
        float fx = x - x0f, fy = y - y0f;
        int offx = (int)x0f - RADIUS - (lvl ? bx1 : bx0);
        int offy = (int)y0f - RADIUS - (lvl ? by1 : by0);
        int cell2 = (offy + a) * EXT + (offx + b);
        int base = lvl * (NCELL * SCSTR) + cell2 * SCSTR + pq;
        float c00 = sC[base];
        float c01 = sC[base + SCSTR];
        float c10 = sC[base + EXT * SCSTR];
        float c11 = sC[base + EXT * SCSTR + SCSTR];
        float v = (1.f - fy) * (1.f - fx) * c00 + (1.f - fy) * fx * c01
                + fy * (1.f - fx) * c10 + fy * fx * c11;
        out[(size_t)e * 882 + (size_t)r * 2 + lvl] = v;
    }
}

extern "C" void kernel_launch(void* const* d_in, const int* in_sizes, int n_in,
                              void* d_out, int out_size, void* d_ws, size_t ws_size,
                              hipStream_t stream) {
    const float* fmap   = (const float*)d_in[0];
    const float* gmap   = (const float*)d_in[1];
    const float* coords = (const float*)d_in[2];
    const int* ii       = (const int*)d_in[3];
    const int* jj       = (const int*)d_in[4];
    float* out = (float*)d_out;

    int E = in_sizes[3];

    float* fm1T  = (float*)d_ws;
    int*   cnt   = (int*)d_ws + FM1SZ;
    int*   off   = cnt + NBKT;
    int*   perm  = off + NBKT;
    float* gmapT = (float*)(perm + E);
    float* fmapT = gmapT + GT_SZ;

    size_t need_perm = ((size_t)FM1SZ + 2 * NBKT + E) * 4;
    size_t need_gT   = need_perm + (size_t)GT_SZ * 4;
    size_t need_fT   = need_gT + FTSZ * 4;

    bool has_fT = ws_size >= need_fT;
    bool has_gT = ws_size >= need_gT;
    bool has_pm = ws_size >= need_perm;

    if (has_fT) {
        transpose_pool<<<N_FR * H1, 256, 0, stream>>>(fmap, fmapT, fm1T);
    } else {
        float* tmp = out;   // scratch; fully overwritten by corr
        int total1 = N_FR * C_CH * H1 * W1;
        pool_kernel<<<(total1 + 255) / 256, 256, 0, stream>>>(fmap, tmp);
        fm1_transpose<<<N_FR * H1, 256, 0, stream>>>(tmp, fm1T);
    }

    if (has_gT) gtrans_kernel<<<M_PT, 128, 0, stream>>>(gmap, gmapT);

    const int* perm_arg = nullptr;
    if (has_pm) {
        int nb = (E + NBKT - 1) / NBKT;
        zero_kernel<<<(2 * NBKT + 255) / 256, 256, 0, stream>>>(cnt);
        hist_kernel<<<nb, NBKT, 0, stream>>>(jj, coords, cnt, E);
        scan_kernel<<<1, 64, 0, stream>>>(cnt, off);
        scatter_kernel<<<nb, NBKT, 0, stream>>>(jj, coords, off, perm, E);
        perm_arg = perm;
    }

    if (has_gT) {
        corr_new<<<E, 128, 0, stream>>>(fmap, has_fT ? fmapT : nullptr, fm1T, gmapT,
                                        coords, ii, jj, perm_arg, out);
    } else {
        corr_old<<<E, 128, 0, stream>>>(fmap, fm1T, gmap, coords, ii, jj, perm_arg, out);
    }
}

// Round 7
// 187.720 us; speedup vs baseline: 2.5899x; 2.5899x over previous
//
#include <hip/hip_runtime.h>

#define RADIUS 3
#define C_CH 128
#define N_FR 16
#define H0 120
#define W0 160
#define HW0 (H0*W0)
#define H1 30
#define W1 40
#define EXT 10
#define NCELL 100
#define M_PT 1536
#define FM1SZ (N_FR*H1*W1*C_CH)     // fm1T floats
#define GT_SZ (M_PT*9*C_CH)         // gmapT floats
#define SCSTR 12                    // sC dword stride per cell
#define NBKT 256                    // sort buckets: frame*16 + y-band

// ---- fused 4x4 pool + transpose: fm0 [N,C,120,160] -> fm1T [N,30,40,C] ----
__global__ __launch_bounds__(256) void pool_fm1T(const float* __restrict__ fm0,
                                                 float* __restrict__ fm1T) {
    __shared__ float s[C_CH * 41];
    int blk = blockIdx.x;          // n*H1 + yo
    int yo = blk % H1;
    int n = blk / H1;
    for (int pair = threadIdx.x; pair < C_CH * W1; pair += 256) {
        int c = pair / W1, xo = pair - c * W1;
        const float* p = fm0 + (((size_t)(n * C_CH + c) * H0) + yo * 4) * W0 + xo * 4;
        float sum = 0.f;
#pragma unroll
        for (int yl = 0; yl < 4; ++yl) {
            float4 v = *reinterpret_cast<const float4*>(p + yl * W0);
            sum += v.x + v.y + v.z + v.w;
        }
        s[c * 41 + xo] = sum * (1.f / 16.f);
    }
    __syncthreads();
    float* dp = fm1T + (size_t)blk * W1 * C_CH;
    for (int t = threadIdx.x; t < W1 * C_CH; t += 256) {
        int xo = t >> 7, c = t & 127;
        dp[t] = s[c * 41 + xo];
    }
}

// ---- gmap [M][C][9] -> gmapT [M][9][C] ----
__global__ __launch_bounds__(128) void gtrans_kernel(const float* __restrict__ g,
                                                     float* __restrict__ gT) {
    int m = blockIdx.x;
    const float* src = g + (size_t)m * (C_CH * 9);
    float* dst = gT + (size_t)m * (C_CH * 9);
    for (int o = threadIdx.x; o < C_CH * 9; o += 128) {
        int c = o & (C_CH - 1);
        int pq = o >> 7;
        dst[o] = src[c * 9 + pq];
    }
}

// ---- (frame, y-band) bucket sort ----
__device__ __forceinline__ int sort_key(const int* jj, const float* coords, int e) {
    float cy = coords[(size_t)e * 18 + 1];
    int by0 = (int)floorf(cy) - RADIUS;
    int band = min(max(by0 >> 3, 0), 15);
    return jj[e] * 16 + band;
}

__global__ void zero_kernel(int* cnt) {
    int t = blockIdx.x * blockDim.x + threadIdx.x;
    if (t < 2 * NBKT) cnt[t] = 0;
}

__global__ void hist_kernel(const int* __restrict__ jj, const float* __restrict__ coords,
                            int* __restrict__ cnt, int E) {
    __shared__ int h[NBKT];
    int tid = threadIdx.x;
    h[tid] = 0;
    __syncthreads();
    int e = blockIdx.x * blockDim.x + tid;
    if (e < E) atomicAdd(&h[sort_key(jj, coords, e)], 1);
    __syncthreads();
    if (h[tid] > 0) atomicAdd(&cnt[tid], h[tid]);
}

__global__ void scan_kernel(const int* __restrict__ cnt, int* __restrict__ off) {
    if (threadIdx.x == 0) {
        int s = 0;
        for (int f = 0; f < NBKT; ++f) { off[f] = s; s += cnt[f]; }
    }
}

__global__ void scatter_kernel(const int* __restrict__ jj, const float* __restrict__ coords,
                               int* __restrict__ off, int* __restrict__ perm, int E) {
    __shared__ int h[NBKT];
    __shared__ int base[NBKT];
    int tid = threadIdx.x;
    h[tid] = 0;
    __syncthreads();
    int e = blockIdx.x * blockDim.x + tid;
    int k = 0, rank = 0;
    if (e < E) {
        k = sort_key(jj, coords, e);
        rank = atomicAdd(&h[k], 1);
    }
    __syncthreads();
    if (h[tid] > 0) base[tid] = atomicAdd(&off[tid], h[tid]);
    __syncthreads();
    if (e < E) perm[base[k] + rank] = e;
}

// ---- corr: R5 structure + bijective XCD chunk swizzle ----
__global__ __launch_bounds__(128) void corr_kernel(
        const float* __restrict__ fmap,   // [N,C,H0,W0]
        const float* __restrict__ fm1T,   // [N,H1,W1,C]
        const float* __restrict__ gmap,   // [M,C,3,3]
        const float* __restrict__ gmapT,  // [M,9,C] or null
        const float* __restrict__ coords, // [E,3,3,2]
        const int* __restrict__ ii,
        const int* __restrict__ jj,
        const int* __restrict__ perm,     // sorted order or null
        float* __restrict__ out) {        // [E,7,7,3,3,2]
    __shared__ float sC[2 * NCELL * SCSTR];   // [lvl][cell][pq]

    // bijective XCD chunk swizzle (m204): XCD x gets a contiguous chunk of the
    // sorted order, so its private L2 sees only ~2 frames instead of all 16.
    int nwg = gridDim.x;
    int q = nwg >> 3, r = nwg & 7;
    int xcd = blockIdx.x & 7;
    int i = blockIdx.x >> 3;
    int orig = (xcd < r ? xcd * (q + 1) : r * (q + 1) + (xcd - r) * q) + i;
    int e = perm ? perm[orig] : orig;

    int tid = threadIdx.x;

    int iie = __builtin_amdgcn_readfirstlane(ii[e]);
    int jje = __builtin_amdgcn_readfirstlane(jj[e]);
    const float* cb = coords + (size_t)e * 18;

    float cx = cb[0], cy = cb[1];
    int bx0 = (int)floorf(cx) - RADIUS;
    int by0 = (int)floorf(cy) - RADIUS;
    int bx1 = (int)floorf(cx * 0.25f) - RADIUS;
    int by1 = (int)floorf(cy * 0.25f) - RADIUS;

    int cell = min(tid, NCELL - 1);
    int iy = cell / EXT, ix = cell - iy * EXT;
    int gy0 = min(max(by0 + iy, 0), H0 - 1);
    int gx0 = min(max(bx0 + ix, 0), W0 - 1);
    int gy1 = min(max(by1 + iy, 0), H1 - 1);
    int gx1 = min(max(bx1 + ix, 0), W1 - 1);

    const float* fp0 = fmap + (size_t)jje * C_CH * HW0 + gy0 * W0 + gx0;
    const float* fp1 = fm1T + (((size_t)jje * H1 + gy1) * W1 + gx1) * C_CH;

    float acc0[9], acc1[9];
#pragma unroll
    for (int pq = 0; pq < 9; ++pq) { acc0[pq] = 0.f; acc1[pq] = 0.f; }

    if (gmapT) {
        const float* gp = gmapT + (size_t)iie * (9 * C_CH);
#pragma unroll 4
        for (int c = 0; c < C_CH; c += 4) {
            float f0 = fp0[(size_t)(c + 0) * HW0];
            float f1 = fp0[(size_t)(c + 1) * HW0];
            float f2 = fp0[(size_t)(c + 2) * HW0];
            float f3 = fp0[(size_t)(c + 3) * HW0];
            float4 fv = *reinterpret_cast<const float4*>(fp1 + c);
#pragma unroll
            for (int pq = 0; pq < 9; ++pq) {
                float4 g4 = *reinterpret_cast<const float4*>(gp + pq * C_CH + c);
                acc0[pq] += f0 * g4.x + f1 * g4.y + f2 * g4.z + f3 * g4.w;
                acc1[pq] += fv.x * g4.x + fv.y * g4.y + fv.z * g4.z + fv.w * g4.w;
            }
        }
    } else {
        const float* gp = gmap + (size_t)iie * (C_CH * 9);
#pragma unroll 2
        for (int c = 0; c < C_CH; c += 4) {
            float f0 = fp0[(size_t)(c + 0) * HW0];
            float f1 = fp0[(size_t)(c + 1) * HW0];
            float f2 = fp0[(size_t)(c + 2) * HW0];
            float f3 = fp0[(size_t)(c + 3) * HW0];
            float4 fv = *reinterpret_cast<const float4*>(fp1 + c);
#pragma unroll
            for (int pq = 0; pq < 9; ++pq) {
                float g0 = gp[(c + 0) * 9 + pq];
                float g1 = gp[(c + 1) * 9 + pq];
                float g2 = gp[(c + 2) * 9 + pq];
                float g3 = gp[(c + 3) * 9 + pq];
                acc0[pq] += f0 * g0 + f1 * g1 + f2 * g2 + f3 * g3;
                acc1[pq] += fv.x * g0 + fv.y * g1 + fv.z * g2 + fv.w * g3;
            }
        }
    }

    if (tid < NCELL) {
        float* s0 = &sC[cell * SCSTR];
        float* s1 = &sC[NCELL * SCSTR + cell * SCSTR];
        *reinterpret_cast<float4*>(s0)     = float4{acc0[0], acc0[1], acc0[2], acc0[3]};
        *reinterpret_cast<float4*>(s0 + 4) = float4{acc0[4], acc0[5], acc0[6], acc0[7]};
        s0[8] = acc0[8];
        *reinterpret_cast<float4*>(s1)     = float4{acc1[0], acc1[1], acc1[2], acc1[3]};
        *reinterpret_cast<float4*>(s1 + 4) = float4{acc1[4], acc1[5], acc1[6], acc1[7]};
        s1[8] = acc1[8];
    }
    __syncthreads();

    for (int o = tid; o < 882; o += 128) {
        int lvl = o & 1;
        int rr = o >> 1;          // (a*7+b)*9 + pq
        int pq = rr % 9;
        int ab = rr / 9;
        int a = ab / 7, b = ab - a * 7;
        float s = lvl ? 0.25f : 1.f;
        float x = cb[pq * 2 + 0] * s;
        float y = cb[pq * 2 + 1] * s;
        float x0f = floorf(x), y0f = floorf(y);
        float fx = x - x0f, fy = y - y0f;
        int offx = (int)x0f - RADIUS - (lvl ? bx1 : bx0);
        int offy = (int)y0f - RADIUS - (lvl ? by1 : by0);
        int cell2 = (offy + a) * EXT + (offx + b);
        int base = lvl * (NCELL * SCSTR) + cell2 * SCSTR + pq;
        float c00 = sC[base];
        float c01 = sC[base + SCSTR];
        float c10 = sC[base + EXT * SCSTR];
        float c11 = sC[base + EXT * SCSTR + SCSTR];
        float v = (1.f - fy) * (1.f - fx) * c00 + (1.f - fy) * fx * c01
                + fy * (1.f - fx) * c10 + fy * fx * c11;
        out[(size_t)e * 882 + (size_t)rr * 2 + lvl] = v;
    }
}

extern "C" void kernel_launch(void* const* d_in, const int* in_sizes, int n_in,
                              void* d_out, int out_size, void* d_ws, size_t ws_size,
                              hipStream_t stream) {
    const float* fmap   = (const float*)d_in[0];
    const float* gmap   = (const float*)d_in[1];
    const float* coords = (const float*)d_in[2];
    const int* ii       = (const int*)d_in[3];
    const int* jj       = (const int*)d_in[4];
    float* out = (float*)d_out;

    int E = in_sizes[3];

    float* fm1T  = (float*)d_ws;                      // FM1SZ floats
    int*   cnt   = (int*)d_ws + FM1SZ;                // [256]
    int*   off   = cnt + NBKT;                        // [256]
    int*   perm  = off + NBKT;                        // [E]
    float* gmapT = (float*)(perm + E);                // GT_SZ floats

    size_t need_perm = ((size_t)FM1SZ + 2 * NBKT + E) * 4;
    size_t need_gT   = need_perm + (size_t)GT_SZ * 4;

    pool_fm1T<<<N_FR * H1, 256, 0, stream>>>(fmap, fm1T);

    const float* gT_arg = nullptr;
    if (ws_size >= need_gT) {
        gtrans_kernel<<<M_PT, 128, 0, stream>>>(gmap, gmapT);
        gT_arg = gmapT;
    }

    const int* perm_arg = nullptr;
    if (ws_size >= need_perm) {
        int nb = (E + NBKT - 1) / NBKT;
        zero_kernel<<<(2 * NBKT + 255) / 256, 256, 0, stream>>>(cnt);
        hist_kernel<<<nb, NBKT, 0, stream>>>(jj, coords, cnt, E);
        scan_kernel<<<1, 64, 0, stream>>>(cnt, off);
        scatter_kernel<<<nb, NBKT, 0, stream>>>(jj, coords, off, perm, E);
        perm_arg = perm;
    }

    corr_kernel<<<E, 128, 0, stream>>>(fmap, fm1T, gmap, gT_arg, coords, ii, jj,
                                       perm_arg, out);
}

// Round 8
// 148.796 us; speedup vs baseline: 3.2674x; 1.2616x over previous
//
#include <hip/hip_runtime.h>

#define RADIUS 3
#define C_CH 128
#define NG 16               // channel groups of 8
#define N_FR 16
#define H0 120
#define W0 160
#define HW0 (H0*W0)
#define H1 30
#define W1 40
#define HW1 (H1*W1)
#define EXT 10
#define NCELL 100
#define M_PT 1536
#define FM1SZ (N_FR*H1*W1*C_CH)
#define GT_SZ (M_PT*9*C_CH)
#define SCSTR 12
#define NBKT 256

typedef _Float16 half2v __attribute__((ext_vector_type(2)));
union Q { uint4 u4; half2v h[4]; };

#if __has_builtin(__builtin_amdgcn_fdot2)
#define FDOT2(a,b,c) __builtin_amdgcn_fdot2((a),(b),(c),false)
#else
#define FDOT2(a,b,c) ((c) + (float)(a).x*(float)(b).x + (float)(a).y*(float)(b).y)
#endif

__device__ __forceinline__ unsigned pack2h(float a, float b) {
    union { _Float16 h[2]; unsigned u; } x;
    x.h[0] = (_Float16)a; x.h[1] = (_Float16)b;
    return x.u;
}

// ---- fmap [N,C,120,160] fp32 -> fH [N,16,120,160,8] f16 ----
__global__ __launch_bounds__(256) void pack_fmap(const float* __restrict__ fm0,
                                                 unsigned* __restrict__ fH) {
    __shared__ float s[8][161];
    int blk = blockIdx.x;       // n*H0 + y
    int y = blk % H0;
    int n = blk / H0;
    for (int g = 0; g < NG; ++g) {
        for (int t = threadIdx.x; t < 8 * W0; t += 256) {
            int c = t / W0, x = t - c * W0;
            s[c][x] = fm0[(((size_t)(n * C_CH + g * 8 + c)) * H0 + y) * W0 + x];
        }
        __syncthreads();
        unsigned* dst = fH + (((size_t)(n * NG + g) * H0 + y) * W0) * 4;
        for (int t = threadIdx.x; t < W0 * 4; t += 256) {
            int x = t >> 2, pr = t & 3;
            dst[t] = pack2h(s[2 * pr][x], s[2 * pr + 1][x]);
        }
        __syncthreads();
    }
}

// ---- fmap -> pooled f16 grouped: f1H [N,16,30,40,8] ----
__global__ __launch_bounds__(256) void pool_pack_fm1(const float* __restrict__ fm0,
                                                     unsigned* __restrict__ f1H) {
    __shared__ float s[8][41];
    int blk = blockIdx.x;      // n*H1 + yo
    int yo = blk % H1;
    int n = blk / H1;
    for (int g = 0; g < NG; ++g) {
        for (int t = threadIdx.x; t < 8 * W1; t += 256) {
            int c = t / W1, xo = t - c * W1;
            const float* p = fm0 + (((size_t)(n * C_CH + g * 8 + c)) * H0 + yo * 4) * W0 + xo * 4;
            float sum = 0.f;
#pragma unroll
            for (int yl = 0; yl < 4; ++yl) {
                float4 v = *reinterpret_cast<const float4*>(p + yl * W0);
                sum += v.x + v.y + v.z + v.w;
            }
            s[c][xo] = sum * (1.f / 16.f);
        }
        __syncthreads();
        unsigned* dst = f1H + (((size_t)(n * NG + g) * H1 + yo) * W1) * 4;
        for (int t = threadIdx.x; t < W1 * 4; t += 256) {
            int xo = t >> 2, pr = t & 3;
            dst[t] = pack2h(s[2 * pr][xo], s[2 * pr + 1][xo]);
        }
        __syncthreads();
    }
}

// ---- gmap [M][128][9] fp32 -> gH [M][9][64] u32 (f16 channel pairs) ----
__global__ __launch_bounds__(128) void gpack(const float* __restrict__ g,
                                             unsigned* __restrict__ gH) {
    __shared__ float s[C_CH * 9];
    int m = blockIdx.x;
    const float* src = g + (size_t)m * (C_CH * 9);
    for (int t = threadIdx.x; t < C_CH * 9; t += 128) s[t] = src[t];
    __syncthreads();
    unsigned* dst = gH + (size_t)m * (9 * 64);
    for (int t = threadIdx.x; t < 9 * 64; t += 128) {
        int pq = t >> 6, pr = t & 63;
        dst[t] = pack2h(s[(2 * pr) * 9 + pq], s[(2 * pr + 1) * 9 + pq]);
    }
}

// ---- fp32 fallback prep (small ws): fused pool+transpose ----
__global__ __launch_bounds__(256) void pool_fm1T(const float* __restrict__ fm0,
                                                 float* __restrict__ fm1T) {
    __shared__ float s[C_CH * 41];
    int blk = blockIdx.x;
    int yo = blk % H1;
    int n = blk / H1;
    for (int pair = threadIdx.x; pair < C_CH * W1; pair += 256) {
        int c = pair / W1, xo = pair - c * W1;
        const float* p = fm0 + (((size_t)(n * C_CH + c) * H0) + yo * 4) * W0 + xo * 4;
        float sum = 0.f;
#pragma unroll
        for (int yl = 0; yl < 4; ++yl) {
            float4 v = *reinterpret_cast<const float4*>(p + yl * W0);
            sum += v.x + v.y + v.z + v.w;
        }
        s[c * 41 + xo] = sum * (1.f / 16.f);
    }
    __syncthreads();
    float* dp = fm1T + (size_t)blk * W1 * C_CH;
    for (int t = threadIdx.x; t < W1 * C_CH; t += 256) {
        int xo = t >> 7, c = t & 127;
        dp[t] = s[c * 41 + xo];
    }
}

__global__ __launch_bounds__(128) void gtrans_kernel(const float* __restrict__ g,
                                                     float* __restrict__ gT) {
    int m = blockIdx.x;
    const float* src = g + (size_t)m * (C_CH * 9);
    float* dst = gT + (size_t)m * (C_CH * 9);
    for (int o = threadIdx.x; o < C_CH * 9; o += 128) {
        int c = o & (C_CH - 1);
        int pq = o >> 7;
        dst[o] = src[c * 9 + pq];
    }
}

// ---- (frame, y-band) bucket sort ----
__device__ __forceinline__ int sort_key(const int* jj, const float* coords, int e) {
    float cy = coords[(size_t)e * 18 + 1];
    int by0 = (int)floorf(cy) - RADIUS;
    int band = min(max(by0 >> 3, 0), 15);
    return jj[e] * 16 + band;
}

__global__ void zero_kernel(int* cnt) {
    int t = blockIdx.x * blockDim.x + threadIdx.x;
    if (t < 2 * NBKT) cnt[t] = 0;
}

__global__ void hist_kernel(const int* __restrict__ jj, const float* __restrict__ coords,
                            int* __restrict__ cnt, int E) {
    __shared__ int h[NBKT];
    int tid = threadIdx.x;
    h[tid] = 0;
    __syncthreads();
    int e = blockIdx.x * blockDim.x + tid;
    if (e < E) atomicAdd(&h[sort_key(jj, coords, e)], 1);
    __syncthreads();
    if (h[tid] > 0) atomicAdd(&cnt[tid], h[tid]);
}

__global__ void scan_kernel(const int* __restrict__ cnt, int* __restrict__ off) {
    if (threadIdx.x == 0) {
        int s = 0;
        for (int f = 0; f < NBKT; ++f) { off[f] = s; s += cnt[f]; }
    }
}

__global__ void scatter_kernel(const int* __restrict__ jj, const float* __restrict__ coords,
                               int* __restrict__ off, int* __restrict__ perm, int E) {
    __shared__ int h[NBKT];
    __shared__ int base[NBKT];
    int tid = threadIdx.x;
    h[tid] = 0;
    __syncthreads();
    int e = blockIdx.x * blockDim.x + tid;
    int k = 0, rank = 0;
    if (e < E) {
        k = sort_key(jj, coords, e);
        rank = atomicAdd(&h[k], 1);
    }
    __syncthreads();
    if (h[tid] > 0) base[tid] = atomicAdd(&off[tid], h[tid]);
    __syncthreads();
    if (e < E) perm[base[k] + rank] = e;
}

// ---- f16 corr: dot2 contraction, grouped-f16 gathers, XCD swizzle ----
__global__ __launch_bounds__(128) void corr_h(
        const unsigned* __restrict__ fH,   // [N,16,H0,W0,4u32]
        const unsigned* __restrict__ f1H,  // [N,16,H1,W1,4u32]
        const unsigned* __restrict__ gH,   // [M,9,64u32]
        const float* __restrict__ coords,
        const int* __restrict__ ii,
        const int* __restrict__ jj,
        const int* __restrict__ perm,
        float* __restrict__ out) {
    __shared__ float sC[2 * NCELL * SCSTR];

    int nwg = gridDim.x;
    int q = nwg >> 3, r = nwg & 7;
    int xcd = blockIdx.x & 7;
    int i = blockIdx.x >> 3;
    int orig = (xcd < r ? xcd * (q + 1) : r * (q + 1) + (xcd - r) * q) + i;
    int e = perm ? perm[orig] : orig;

    int tid = threadIdx.x;
    int iie = __builtin_amdgcn_readfirstlane(ii[e]);
    int jje = __builtin_amdgcn_readfirstlane(jj[e]);
    const float* cb = coords + (size_t)e * 18;

    float cx = cb[0], cy = cb[1];
    int bx0 = (int)floorf(cx) - RADIUS;
    int by0 = (int)floorf(cy) - RADIUS;
    int bx1 = (int)floorf(cx * 0.25f) - RADIUS;
    int by1 = (int)floorf(cy * 0.25f) - RADIUS;

    int cell = min(tid, NCELL - 1);
    int iy = cell / EXT, ix = cell - iy * EXT;
    int gy0 = min(max(by0 + iy, 0), H0 - 1);
    int gx0 = min(max(bx0 + ix, 0), W0 - 1);
    int gy1 = min(max(by1 + iy, 0), H1 - 1);
    int gx1 = min(max(bx1 + ix, 0), W1 - 1);

    const uint4* f0p = (const uint4*)fH + ((size_t)jje * NG * HW0 + (size_t)gy0 * W0 + gx0);
    const uint4* f1p = (const uint4*)f1H + ((size_t)jje * NG * HW1 + (size_t)gy1 * W1 + gx1);
    const uint4* gp  = (const uint4*)gH + (size_t)iie * 144;   // [9][16] uint4

    float acc0[9], acc1[9];
#pragma unroll
    for (int pq = 0; pq < 9; ++pq) { acc0[pq] = 0.f; acc1[pq] = 0.f; }

#pragma unroll 4
    for (int g = 0; g < NG; ++g) {
        Q a0; a0.u4 = f0p[(size_t)g * HW0];
        Q a1; a1.u4 = f1p[(size_t)g * HW1];
#pragma unroll
        for (int pq = 0; pq < 9; ++pq) {
            Q gg; gg.u4 = gp[pq * 16 + g];
#pragma unroll
            for (int k = 0; k < 4; ++k) {
                acc0[pq] = FDOT2(a0.h[k], gg.h[k], acc0[pq]);
                acc1[pq] = FDOT2(a1.h[k], gg.h[k], acc1[pq]);
            }
        }
    }

    if (tid < NCELL) {
        float* s0 = &sC[cell * SCSTR];
        float* s1 = &sC[NCELL * SCSTR + cell * SCSTR];
        *reinterpret_cast<float4*>(s0)     = float4{acc0[0], acc0[1], acc0[2], acc0[3]};
        *reinterpret_cast<float4*>(s0 + 4) = float4{acc0[4], acc0[5], acc0[6], acc0[7]};
        s0[8] = acc0[8];
        *reinterpret_cast<float4*>(s1)     = float4{acc1[0], acc1[1], acc1[2], acc1[3]};
        *reinterpret_cast<float4*>(s1 + 4) = float4{acc1[4], acc1[5], acc1[6], acc1[7]};
        s1[8] = acc1[8];
    }
    __syncthreads();

    for (int o = tid; o < 882; o += 128) {
        int lvl = o & 1;
        int rr = o >> 1;
        int pq = rr % 9;
        int ab = rr / 9;
        int a = ab / 7, b = ab - a * 7;
        float s = lvl ? 0.25f : 1.f;
        float x = cb[pq * 2 + 0] * s;
        float y = cb[pq * 2 + 1] * s;
        float x0f = floorf(x), y0f = floorf(y);
        float fx = x - x0f, fy = y - y0f;
        int offx = (int)x0f - RADIUS - (lvl ? bx1 : bx0);
        int offy = (int)y0f - RADIUS - (lvl ? by1 : by0);
        int cell2 = (offy + a) * EXT + (offx + b);
        int base = lvl * (NCELL * SCSTR) + cell2 * SCSTR + pq;
        float c00 = sC[base];
        float c01 = sC[base + SCSTR];
        float c10 = sC[base + EXT * SCSTR];
        float c11 = sC[base + EXT * SCSTR + SCSTR];
        float v = (1.f - fy) * (1.f - fx) * c00 + (1.f - fy) * fx * c01
                + fy * (1.f - fx) * c10 + fy * fx * c11;
        out[(size_t)e * 882 + (size_t)rr * 2 + lvl] = v;
    }
}

// ---- fp32 fallback corr (R7) ----
__global__ __launch_bounds__(128) void corr_kernel(
        const float* __restrict__ fmap, const float* __restrict__ fm1T,
        const float* __restrict__ gmap, const float* __restrict__ gmapT,
        const float* __restrict__ coords, const int* __restrict__ ii,
        const int* __restrict__ jj, const int* __restrict__ perm,
        float* __restrict__ out) {
    __shared__ float sC[2 * NCELL * SCSTR];
    int nwg = gridDim.x;
    int q = nwg >> 3, r = nwg & 7;
    int xcd = blockIdx.x & 7;
    int i = blockIdx.x >> 3;
    int orig = (xcd < r ? xcd * (q + 1) : r * (q + 1) + (xcd - r) * q) + i;
    int e = perm ? perm[orig] : orig;
    int tid = threadIdx.x;
    int iie = __builtin_amdgcn_readfirstlane(ii[e]);
    int jje = __builtin_amdgcn_readfirstlane(jj[e]);
    const float* cb = coords + (size_t)e * 18;
    float cx = cb[0], cy = cb[1];
    int bx0 = (int)floorf(cx) - RADIUS;
    int by0 = (int)floorf(cy) - RADIUS;
    int bx1 = (int)floorf(cx * 0.25f) - RADIUS;
    int by1 = (int)floorf(cy * 0.25f) - RADIUS;
    int cell = min(tid, NCELL - 1);
    int iy = cell / EXT, ix = cell - iy * EXT;
    int gy0 = min(max(by0 + iy, 0), H0 - 1);
    int gx0 = min(max(bx0 + ix, 0), W0 - 1);
    int gy1 = min(max(by1 + iy, 0), H1 - 1);
    int gx1 = min(max(bx1 + ix, 0), W1 - 1);
    const float* fp0 = fmap + (size_t)jje * C_CH * HW0 + gy0 * W0 + gx0;
    const float* fp1 = fm1T + (((size_t)jje * H1 + gy1) * W1 + gx1) * C_CH;
    float acc0[9], acc1[9];
#pragma unroll
    for (int pq = 0; pq < 9; ++pq) { acc0[pq] = 0.f; acc1[pq] = 0.f; }
    if (gmapT) {
        const float* gp = gmapT + (size_t)iie * (9 * C_CH);
#pragma unroll 4
        for (int c = 0; c < C_CH; c += 4) {
            float f0 = fp0[(size_t)(c + 0) * HW0];
            float f1 = fp0[(size_t)(c + 1) * HW0];
            float f2 = fp0[(size_t)(c + 2) * HW0];
            float f3 = fp0[(size_t)(c + 3) * HW0];
            float4 fv = *reinterpret_cast<const float4*>(fp1 + c);
#pragma unroll
            for (int pq = 0; pq < 9; ++pq) {
                float4 g4 = *reinterpret_cast<const float4*>(gp + pq * C_CH + c);
                acc0[pq] += f0 * g4.x + f1 * g4.y + f2 * g4.z + f3 * g4.w;
                acc1[pq] += fv.x * g4.x + fv.y * g4.y + fv.z * g4.z + fv.w * g4.w;
            }
        }
    } else {
        const float* gp = gmap + (size_t)iie * (C_CH * 9);
#pragma unroll 2
        for (int c = 0; c < C_CH; c += 4) {
            float f0 = fp0[(size_t)(c + 0) * HW0];
            float f1 = fp0[(size_t)(c + 1) * HW0];
            float f2 = fp0[(size_t)(c + 2) * HW0];
            float f3 = fp0[(size_t)(c + 3) * HW0];
            float4 fv = *reinterpret_cast<const float4*>(fp1 + c);
#pragma unroll
            for (int pq = 0; pq < 9; ++pq) {
                float g0 = gp[(c + 0) * 9 + pq];
                float g1 = gp[(c + 1) * 9 + pq];
                float g2 = gp[(c + 2) * 9 + pq];
                float g3 = gp[(c + 3) * 9 + pq];
                acc0[pq] += f0 * g0 + f1 * g1 + f2 * g2 + f3 * g3;
                acc1[pq] += fv.x * g0 + fv.y * g1 + fv.z * g2 + fv.w * g3;
            }
        }
    }
    if (tid < NCELL) {
        float* s0 = &sC[cell * SCSTR];
        float* s1 = &sC[NCELL * SCSTR + cell * SCSTR];
        *reinterpret_cast<float4*>(s0)     = float4{acc0[0], acc0[1], acc0[2], acc0[3]};
        *reinterpret_cast<float4*>(s0 + 4) = float4{acc0[4], acc0[5], acc0[6], acc0[7]};
        s0[8] = acc0[8];
        *reinterpret_cast<float4*>(s1)     = float4{acc1[0], acc1[1], acc1[2], acc1[3]};
        *reinterpret_cast<float4*>(s1 + 4) = float4{acc1[4], acc1[5], acc1[6], acc1[7]};
        s1[8] = acc1[8];
    }
    __syncthreads();
    for (int o = tid; o < 882; o += 128) {
        int lvl = o & 1;
        int rr = o >> 1;
        int pq = rr % 9;
        int ab = rr / 9;
        int a = ab / 7, b = ab - a * 7;
        float s = lvl ? 0.25f : 1.f;
        float x = cb[pq * 2 + 0] * s;
        float y = cb[pq * 2 + 1] * s;
        float x0f = floorf(x), y0f = floorf(y);
        float fx = x - x0f, fy = y - y0f;
        int offx = (int)x0f - RADIUS - (lvl ? bx1 : bx0);
        int offy = (int)y0f - RADIUS - (lvl ? by1 : by0);
        int cell2 = (offy + a) * EXT + (offx + b);
        int base = lvl * (NCELL * SCSTR) + cell2 * SCSTR + pq;
        float c00 = sC[base];
        float c01 = sC[base + SCSTR];
        float c10 = sC[base + EXT * SCSTR];
        float c11 = sC[base + EXT * SCSTR + SCSTR];
        float v = (1.f - fy) * (1.f - fx) * c00 + (1.f - fy) * fx * c01
                + fy * (1.f - fx) * c10 + fy * fx * c11;
        out[(size_t)e * 882 + (size_t)rr * 2 + lvl] = v;
    }
}

extern "C" void kernel_launch(void* const* d_in, const int* in_sizes, int n_in,
                              void* d_out, int out_size, void* d_ws, size_t ws_size,
                              hipStream_t stream) {
    const float* fmap   = (const float*)d_in[0];
    const float* gmap   = (const float*)d_in[1];
    const float* coords = (const float*)d_in[2];
    const int* ii       = (const int*)d_in[3];
    const int* jj       = (const int*)d_in[4];
    float* out = (float*)d_out;
    int E = in_sizes[3];

    size_t szFH  = (size_t)N_FR * C_CH * HW0 * 2;   // 78.6 MB
    size_t szF1H = (size_t)N_FR * C_CH * HW1 * 2;   // 4.9 MB
    size_t szGH  = (size_t)M_PT * 9 * C_CH * 2;     // 3.5 MB
    size_t need_h = szFH + szF1H + szGH + 2048 + (size_t)E * 4;

    if (ws_size >= need_h) {
        unsigned* fH  = (unsigned*)d_ws;
        unsigned* f1H = (unsigned*)((char*)d_ws + szFH);
        unsigned* gH  = (unsigned*)((char*)d_ws + szFH + szF1H);
        int* cnt  = (int*)((char*)d_ws + szFH + szF1H + szGH);
        int* off  = cnt + NBKT;
        int* perm = off + NBKT;

        pack_fmap<<<N_FR * H0, 256, 0, stream>>>(fmap, fH);
        pool_pack_fm1<<<N_FR * H1, 256, 0, stream>>>(fmap, f1H);
        gpack<<<M_PT, 128, 0, stream>>>(gmap, gH);

        int nb = (E + NBKT - 1) / NBKT;
        zero_kernel<<<(2 * NBKT + 255) / 256, 256, 0, stream>>>(cnt);
        hist_kernel<<<nb, NBKT, 0, stream>>>(jj, coords, cnt, E);
        scan_kernel<<<1, 64, 0, stream>>>(cnt, off);
        scatter_kernel<<<nb, NBKT, 0, stream>>>(jj, coords, off, perm, E);

        corr_h<<<E, 128, 0, stream>>>(fH, f1H, gH, coords, ii, jj, perm, out);
        return;
    }

    // ---- fp32 fallback (R7 path) ----
    float* fm1T  = (float*)d_ws;
    int*   cnt   = (int*)d_ws + FM1SZ;
    int*   off   = cnt + NBKT;
    int*   perm  = off + NBKT;
    float* gmapT = (float*)(perm + E);

    size_t need_perm = ((size_t)FM1SZ + 2 * NBKT + E) * 4;
    size_t need_gT   = need_perm + (size_t)GT_SZ * 4;

    pool_fm1T<<<N_FR * H1, 256, 0, stream>>>(fmap, fm1T);

    const float* gT_arg = nullptr;
    if (ws_size >= need_gT) {
        gtrans_kernel<<<M_PT, 128, 0, stream>>>(gmap, gmapT);
        gT_arg = gmapT;
    }
    const int* perm_arg = nullptr;
    if (ws_size >= need_perm) {
        int nb = (E + NBKT - 1) / NBKT;
        zero_kernel<<<(2 * NBKT + 255) / 256, 256, 0, stream>>>(cnt);
        hist_kernel<<<nb, NBKT, 0, stream>>>(jj, coords, cnt, E);
        scan_kernel<<<1, 64, 0, stream>>>(cnt, off);
        scatter_kernel<<<nb, NBKT, 0, stream>>>(jj, coords, off, perm, E);
        perm_arg = perm;
    }
    corr_kernel<<<E, 128, 0, stream>>>(fmap, fm1T, gmap, gT_arg, coords, ii, jj,
                                       perm_arg, out);
}

// Round 9
// 123.222 us; speedup vs baseline: 3.9456x; 1.2075x over previous
//
#include <hip/hip_runtime.h>

#define RADIUS 3
#define C_CH 128
#define NG 16               // channel groups of 8
#define N_FR 16
#define H0 120
#define W0 160
#define HW0 (H0*W0)
#define H1 30
#define W1 40
#define HW1 (H1*W1)
#define EXT 10
#define NCELL 100
#define M_PT 1536
#define FM1SZ (N_FR*H1*W1*C_CH)
#define GT_SZ (M_PT*9*C_CH)
#define SCSTR 12
#define NBKT 256

typedef _Float16 half2v __attribute__((ext_vector_type(2)));
union Q { uint4 u4; half2v h[4]; };

#if __has_builtin(__builtin_amdgcn_fdot2)
#define FDOT2(a,b,c) __builtin_amdgcn_fdot2((a),(b),(c),false)
#else
#define FDOT2(a,b,c) ((c) + (float)(a).x*(float)(b).x + (float)(a).y*(float)(b).y)
#endif

__device__ __forceinline__ unsigned pack2h(float a, float b) {
    union { _Float16 h[2]; unsigned u; } x;
    x.h[0] = (_Float16)a; x.h[1] = (_Float16)b;
    return x.u;
}

// ---- LDS-free pack: fmap [N,C,120,160] fp32 -> fH [N,16,120,160] uint4 (8 f16) ----
__global__ __launch_bounds__(256) void pack_fmap2(const float* __restrict__ fm0,
                                                  uint4* __restrict__ fH) {
    int idx = blockIdx.x * 256 + threadIdx.x;     // (n*NG + g)*HW0 + xy
    int total = N_FR * NG * HW0;
    if (idx >= total) return;
    int xy = idx % HW0;
    int g = (idx / HW0) & (NG - 1);
    int n = idx / (HW0 * NG);
    const float* src = fm0 + ((size_t)(n * C_CH + g * 8)) * HW0 + xy;
    uint4 o;
    o.x = pack2h(src[0],          src[(size_t)HW0]);
    o.y = pack2h(src[2*(size_t)HW0], src[3*(size_t)HW0]);
    o.z = pack2h(src[4*(size_t)HW0], src[5*(size_t)HW0]);
    o.w = pack2h(src[6*(size_t)HW0], src[7*(size_t)HW0]);
    fH[idx] = o;
}

// ---- pool from packed f16: fH -> f1H [N,16,30,40] uint4 ----
__global__ __launch_bounds__(256) void pool_from_fH(const uint4* __restrict__ fH,
                                                    uint4* __restrict__ f1H) {
    int idx = blockIdx.x * 256 + threadIdx.x;     // (n*NG + g)*HW1 + yo*W1 + xo
    int total = N_FR * NG * HW1;
    if (idx >= total) return;
    int xo = idx % W1;
    int yo = (idx / W1) % H1;
    int ng = idx / HW1;
    const uint4* src = fH + ((size_t)ng * H0 + yo * 4) * W0 + xo * 4;
    float s[8];
#pragma unroll
    for (int k = 0; k < 8; ++k) s[k] = 0.f;
#pragma unroll
    for (int yl = 0; yl < 4; ++yl) {
#pragma unroll
        for (int dx = 0; dx < 4; ++dx) {
            Q q; q.u4 = src[(size_t)yl * W0 + dx];
#pragma unroll
            for (int k = 0; k < 4; ++k) {
                s[2*k]   += (float)q.h[k].x;
                s[2*k+1] += (float)q.h[k].y;
            }
        }
    }
    uint4 o;
    o.x = pack2h(s[0] * (1.f/16.f), s[1] * (1.f/16.f));
    o.y = pack2h(s[2] * (1.f/16.f), s[3] * (1.f/16.f));
    o.z = pack2h(s[4] * (1.f/16.f), s[5] * (1.f/16.f));
    o.w = pack2h(s[6] * (1.f/16.f), s[7] * (1.f/16.f));
    f1H[idx] = o;
}

// ---- gmap [M][128][9] fp32 -> gH [M][9][64] u32 (f16 channel pairs) ----
__global__ __launch_bounds__(128) void gpack(const float* __restrict__ g,
                                             unsigned* __restrict__ gH) {
    __shared__ float s[C_CH * 9];
    int m = blockIdx.x;
    const float* src = g + (size_t)m * (C_CH * 9);
    for (int t = threadIdx.x; t < C_CH * 9; t += 128) s[t] = src[t];
    __syncthreads();
    unsigned* dst = gH + (size_t)m * (9 * 64);
    for (int t = threadIdx.x; t < 9 * 64; t += 128) {
        int pq = t >> 6, pr = t & 63;
        dst[t] = pack2h(s[(2 * pr) * 9 + pq], s[(2 * pr + 1) * 9 + pq]);
    }
}

// ---- (frame, y-band) bucket sort ----
__device__ __forceinline__ int sort_key(const int* jj, const float* coords, int e) {
    float cy = coords[(size_t)e * 18 + 1];
    int by0 = (int)floorf(cy) - RADIUS;
    int band = min(max(by0 >> 3, 0), 15);
    return jj[e] * 16 + band;
}

__global__ void zero_kernel(int* cnt) {
    int t = blockIdx.x * blockDim.x + threadIdx.x;
    if (t < 2 * NBKT) cnt[t] = 0;
}

__global__ void hist_kernel(const int* __restrict__ jj, const float* __restrict__ coords,
                            int* __restrict__ cnt, int E) {
    __shared__ int h[NBKT];
    int tid = threadIdx.x;
    h[tid] = 0;
    __syncthreads();
    int e = blockIdx.x * blockDim.x + tid;
    if (e < E) atomicAdd(&h[sort_key(jj, coords, e)], 1);
    __syncthreads();
    if (h[tid] > 0) atomicAdd(&cnt[tid], h[tid]);
}

__global__ void scan_kernel(const int* __restrict__ cnt, int* __restrict__ off) {
    if (threadIdx.x == 0) {
        int s = 0;
        for (int f = 0; f < NBKT; ++f) { off[f] = s; s += cnt[f]; }
    }
}

__global__ void scatter_kernel(const int* __restrict__ jj, const float* __restrict__ coords,
                               int* __restrict__ off, int* __restrict__ perm, int E) {
    __shared__ int h[NBKT];
    __shared__ int base[NBKT];
    int tid = threadIdx.x;
    h[tid] = 0;
    __syncthreads();
    int e = blockIdx.x * blockDim.x + tid;
    int k = 0, rank = 0;
    if (e < E) {
        k = sort_key(jj, coords, e);
        rank = atomicAdd(&h[k], 1);
    }
    __syncthreads();
    if (h[tid] > 0) base[tid] = atomicAdd(&off[tid], h[tid]);
    __syncthreads();
    if (e < E) perm[base[k] + rank] = e;
}

// ---- f16 corr: dot2 contraction, grouped-f16 gathers, XCD swizzle ----
__global__ __launch_bounds__(128) void corr_h(
        const unsigned* __restrict__ fH,   // [N,16,H0,W0,4u32]
        const unsigned* __restrict__ f1H,  // [N,16,H1,W1,4u32]
        const unsigned* __restrict__ gH,   // [M,9,64u32]
        const float* __restrict__ coords,
        const int* __restrict__ ii,
        const int* __restrict__ jj,
        const int* __restrict__ perm,
        float* __restrict__ out) {
    __shared__ float sC[2 * NCELL * SCSTR];

    int nwg = gridDim.x;
    int q = nwg >> 3, r = nwg & 7;
    int xcd = blockIdx.x & 7;
    int i = blockIdx.x >> 3;
    int orig = (xcd < r ? xcd * (q + 1) : r * (q + 1) + (xcd - r) * q) + i;
    int e = perm ? perm[orig] : orig;

    int tid = threadIdx.x;
    int iie = __builtin_amdgcn_readfirstlane(ii[e]);
    int jje = __builtin_amdgcn_readfirstlane(jj[e]);
    const float* cb = coords + (size_t)e * 18;

    float cx = cb[0], cy = cb[1];
    int bx0 = (int)floorf(cx) - RADIUS;
    int by0 = (int)floorf(cy) - RADIUS;
    int bx1 = (int)floorf(cx * 0.25f) - RADIUS;
    int by1 = (int)floorf(cy * 0.25f) - RADIUS;

    int cell = min(tid, NCELL - 1);
    int iy = cell / EXT, ix = cell - iy * EXT;
    int gy0 = min(max(by0 + iy, 0), H0 - 1);
    int gx0 = min(max(bx0 + ix, 0), W0 - 1);
    int gy1 = min(max(by1 + iy, 0), H1 - 1);
    int gx1 = min(max(bx1 + ix, 0), W1 - 1);

    const uint4* f0p = (const uint4*)fH + ((size_t)jje * NG * HW0 + (size_t)gy0 * W0 + gx0);
    const uint4* f1p = (const uint4*)f1H + ((size_t)jje * NG * HW1 + (size_t)gy1 * W1 + gx1);
    const uint4* gp  = (const uint4*)gH + (size_t)iie * 144;   // [9][16] uint4

    float acc0[9], acc1[9];
#pragma unroll
    for (int pq = 0; pq < 9; ++pq) { acc0[pq] = 0.f; acc1[pq] = 0.f; }

#pragma unroll 4
    for (int g = 0; g < NG; ++g) {
        Q a0; a0.u4 = f0p[(size_t)g * HW0];
        Q a1; a1.u4 = f1p[(size_t)g * HW1];
#pragma unroll
        for (int pq = 0; pq < 9; ++pq) {
            Q gg; gg.u4 = gp[pq * 16 + g];
#pragma unroll
            for (int k = 0; k < 4; ++k) {
                acc0[pq] = FDOT2(a0.h[k], gg.h[k], acc0[pq]);
                acc1[pq] = FDOT2(a1.h[k], gg.h[k], acc1[pq]);
            }
        }
    }

    if (tid < NCELL) {
        float* s0 = &sC[cell * SCSTR];
        float* s1 = &sC[NCELL * SCSTR + cell * SCSTR];
        *reinterpret_cast<float4*>(s0)     = float4{acc0[0], acc0[1], acc0[2], acc0[3]};
        *reinterpret_cast<float4*>(s0 + 4) = float4{acc0[4], acc0[5], acc0[6], acc0[7]};
        s0[8] = acc0[8];
        *reinterpret_cast<float4*>(s1)     = float4{acc1[0], acc1[1], acc1[2], acc1[3]};
        *reinterpret_cast<float4*>(s1 + 4) = float4{acc1[4], acc1[5], acc1[6], acc1[7]};
        s1[8] = acc1[8];
    }
    __syncthreads();

    for (int o = tid; o < 882; o += 128) {
        int lvl = o & 1;
        int rr = o >> 1;
        int pq = rr % 9;
        int ab = rr / 9;
        int a = ab / 7, b = ab - a * 7;
        float s = lvl ? 0.25f : 1.f;
        float x = cb[pq * 2 + 0] * s;
        float y = cb[pq * 2 + 1] * s;
        float x0f = floorf(x), y0f = floorf(y);
        float fx = x - x0f, fy = y - y0f;
        int offx = (int)x0f - RADIUS - (lvl ? bx1 : bx0);
        int offy = (int)y0f - RADIUS - (lvl ? by1 : by0);
        int cell2 = (offy + a) * EXT + (offx + b);
        int base = lvl * (NCELL * SCSTR) + cell2 * SCSTR + pq;
        float c00 = sC[base];
        float c01 = sC[base + SCSTR];
        float c10 = sC[base + EXT * SCSTR];
        float c11 = sC[base + EXT * SCSTR + SCSTR];
        float v = (1.f - fy) * (1.f - fx) * c00 + (1.f - fy) * fx * c01
                + fy * (1.f - fx) * c10 + fy * fx * c11;
        out[(size_t)e * 882 + (size_t)rr * 2 + lvl] = v;
    }
}

// ---- fp32 fallback (R7 path) ----
__global__ __launch_bounds__(256) void pool_fm1T(const float* __restrict__ fm0,
                                                 float* __restrict__ fm1T) {
    __shared__ float s[C_CH * 41];
    int blk = blockIdx.x;
    int yo = blk % H1;
    int n = blk / H1;
    for (int pair = threadIdx.x; pair < C_CH * W1; pair += 256) {
        int c = pair / W1, xo = pair - c * W1;
        const float* p = fm0 + (((size_t)(n * C_CH + c) * H0) + yo * 4) * W0 + xo * 4;
        float sum = 0.f;
#pragma unroll
        for (int yl = 0; yl < 4; ++yl) {
            float4 v = *reinterpret_cast<const float4*>(p + yl * W0);
            sum += v.x + v.y + v.z + v.w;
        }
        s[c * 41 + xo] = sum * (1.f / 16.f);
    }
    __syncthreads();
    float* dp = fm1T + (size_t)blk * W1 * C_CH;
    for (int t = threadIdx.x; t < W1 * C_CH; t += 256) {
        int xo = t >> 7, c = t & 127;
        dp[t] = s[c * 41 + xo];
    }
}

__global__ __launch_bounds__(128) void corr_kernel(
        const float* __restrict__ fmap, const float* __restrict__ fm1T,
        const float* __restrict__ gmap, const float* __restrict__ coords,
        const int* __restrict__ ii, const int* __restrict__ jj,
        float* __restrict__ out) {
    __shared__ float sC[2 * NCELL * SCSTR];
    int e = blockIdx.x;
    int tid = threadIdx.x;
    int iie = __builtin_amdgcn_readfirstlane(ii[e]);
    int jje = __builtin_amdgcn_readfirstlane(jj[e]);
    const float* cb = coords + (size_t)e * 18;
    float cx = cb[0], cy = cb[1];
    int bx0 = (int)floorf(cx) - RADIUS;
    int by0 = (int)floorf(cy) - RADIUS;
    int bx1 = (int)floorf(cx * 0.25f) - RADIUS;
    int by1 = (int)floorf(cy * 0.25f) - RADIUS;
    int cell = min(tid, NCELL - 1);
    int iy = cell / EXT, ix = cell - iy * EXT;
    int gy0 = min(max(by0 + iy, 0), H0 - 1);
    int gx0 = min(max(bx0 + ix, 0), W0 - 1);
    int gy1 = min(max(by1 + iy, 0), H1 - 1);
    int gx1 = min(max(bx1 + ix, 0), W1 - 1);
    const float* fp0 = fmap + (size_t)jje * C_CH * HW0 + gy0 * W0 + gx0;
    const float* fp1 = fm1T + (((size_t)jje * H1 + gy1) * W1 + gx1) * C_CH;
    float acc0[9], acc1[9];
#pragma unroll
    for (int pq = 0; pq < 9; ++pq) { acc0[pq] = 0.f; acc1[pq] = 0.f; }
    const float* gp = gmap + (size_t)iie * (C_CH * 9);
#pragma unroll 2
    for (int c = 0; c < C_CH; c += 4) {
        float f0 = fp0[(size_t)(c + 0) * HW0];
        float f1 = fp0[(size_t)(c + 1) * HW0];
        float f2 = fp0[(size_t)(c + 2) * HW0];
        float f3 = fp0[(size_t)(c + 3) * HW0];
        float4 fv = *reinterpret_cast<const float4*>(fp1 + c);
#pragma unroll
        for (int pq = 0; pq < 9; ++pq) {
            float g0 = gp[(c + 0) * 9 + pq];
            float g1 = gp[(c + 1) * 9 + pq];
            float g2 = gp[(c + 2) * 9 + pq];
            float g3 = gp[(c + 3) * 9 + pq];
            acc0[pq] += f0 * g0 + f1 * g1 + f2 * g2 + f3 * g3;
            acc1[pq] += fv.x * g0 + fv.y * g1 + fv.z * g2 + fv.w * g3;
        }
    }
    if (tid < NCELL) {
        float* s0 = &sC[cell * SCSTR];
        float* s1 = &sC[NCELL * SCSTR + cell * SCSTR];
        *reinterpret_cast<float4*>(s0)     = float4{acc0[0], acc0[1], acc0[2], acc0[3]};
        *reinterpret_cast<float4*>(s0 + 4) = float4{acc0[4], acc0[5], acc0[6], acc0[7]};
        s0[8] = acc0[8];
        *reinterpret_cast<float4*>(s1)     = float4{acc1[0], acc1[1], acc1[2], acc1[3]};
        *reinterpret_cast<float4*>(s1 + 4) = float4{acc1[4], acc1[5], acc1[6], acc1[7]};
        s1[8] = acc1[8];
    }
    __syncthreads();
    for (int o = tid; o < 882; o += 128) {
        int lvl = o & 1;
        int rr = o >> 1;
        int pq = rr % 9;
        int ab = rr / 9;
        int a = ab / 7, b = ab - a * 7;
        float s = lvl ? 0.25f : 1.f;
        float x = cb[pq * 2 + 0] * s;
        float y = cb[pq * 2 + 1] * s;
        float x0f = floorf(x), y0f = floorf(y);
        float fx = x - x0f, fy = y - y0f;
        int offx = (int)x0f - RADIUS - (lvl ? bx1 : bx0);
        int offy = (int)y0f - RADIUS - (lvl ? by1 : by0);
        int cell2 = (offy + a) * EXT + (offx + b);
        int base = lvl * (NCELL * SCSTR) + cell2 * SCSTR + pq;
        float c00 = sC[base];
        float c01 = sC[base + SCSTR];
        float c10 = sC[base + EXT * SCSTR];
        float c11 = sC[base + EXT * SCSTR + SCSTR];
        float v = (1.f - fy) * (1.f - fx) * c00 + (1.f - fy) * fx * c01
                + fy * (1.f - fx) * c10 + fy * fx * c11;
        out[(size_t)e * 882 + (size_t)rr * 2 + lvl] = v;
    }
}

extern "C" void kernel_launch(void* const* d_in, const int* in_sizes, int n_in,
                              void* d_out, int out_size, void* d_ws, size_t ws_size,
                              hipStream_t stream) {
    const float* fmap   = (const float*)d_in[0];
    const float* gmap   = (const float*)d_in[1];
    const float* coords = (const float*)d_in[2];
    const int* ii       = (const int*)d_in[3];
    const int* jj       = (const int*)d_in[4];
    float* out = (float*)d_out;
    int E = in_sizes[3];

    size_t szFH  = (size_t)N_FR * C_CH * HW0 * 2;   // 78.6 MB
    size_t szF1H = (size_t)N_FR * C_CH * HW1 * 2;   // 4.9 MB
    size_t szGH  = (size_t)M_PT * 9 * C_CH * 2;     // 3.5 MB
    size_t need_h = szFH + szF1H + szGH + 2048 + (size_t)E * 4;

    if (ws_size >= need_h) {
        uint4* fH  = (uint4*)d_ws;
        uint4* f1H = (uint4*)((char*)d_ws + szFH);
        unsigned* gH = (unsigned*)((char*)d_ws + szFH + szF1H);
        int* cnt  = (int*)((char*)d_ws + szFH + szF1H + szGH);
        int* off  = cnt + NBKT;
        int* perm = off + NBKT;

        int tot_pack = N_FR * NG * HW0;
        pack_fmap2<<<(tot_pack + 255) / 256, 256, 0, stream>>>(fmap, fH);
        int tot_pool = N_FR * NG * HW1;
        pool_from_fH<<<(tot_pool + 255) / 256, 256, 0, stream>>>(fH, f1H);
        gpack<<<M_PT, 128, 0, stream>>>(gmap, gH);

        int nb = (E + NBKT - 1) / NBKT;
        zero_kernel<<<(2 * NBKT + 255) / 256, 256, 0, stream>>>(cnt);
        hist_kernel<<<nb, NBKT, 0, stream>>>(jj, coords, cnt, E);
        scan_kernel<<<1, 64, 0, stream>>>(cnt, off);
        scatter_kernel<<<nb, NBKT, 0, stream>>>(jj, coords, off, perm, E);

        corr_h<<<E, 128, 0, stream>>>((const unsigned*)fH, (const unsigned*)f1H, gH,
                                      coords, ii, jj, perm, out);
        return;
    }

    // ---- fp32 fallback ----
    float* fm1T = (float*)d_ws;
    pool_fm1T<<<N_FR * H1, 256, 0, stream>>>(fmap, fm1T);
    corr_kernel<<<E, 128, 0, stream>>>(fmap, fm1T, gmap, coords, ii, jj, out);
}

// Round 10
// 113.311 us; speedup vs baseline: 4.2907x; 1.0875x over previous
//
#include <hip/hip_runtime.h>

#define RADIUS 3
#define C_CH 128
#define NG 16               // channel groups of 8
#define N_FR 16
#define H0 120
#define W0 160
#define HW0 (H0*W0)
#define H1 30
#define W1 40
#define HW1 (H1*W1)
#define EXT 10
#define NCELL 100
#define M_PT 1536
#define FM1SZ (N_FR*H1*W1*C_CH)
#define SCSTR 12
#define NBKT 256

typedef _Float16 half2v __attribute__((ext_vector_type(2)));
typedef _Float16 f16x8 __attribute__((ext_vector_type(8)));
typedef float f32x4 __attribute__((ext_vector_type(4)));
union Q { uint4 u4; half2v h[4]; };
union AB { uint4 u4; f16x8 h8; };

__device__ __forceinline__ unsigned pack2h(float a, float b) {
    union { _Float16 h[2]; unsigned u; } x;
    x.h[0] = (_Float16)a; x.h[1] = (_Float16)b;
    return x.u;
}

// ---- LDS-free pack: fmap [N,C,120,160] fp32 -> fH [N,16,120,160] uint4 (8 f16) ----
__global__ __launch_bounds__(256) void pack_fmap2(const float* __restrict__ fm0,
                                                  uint4* __restrict__ fH) {
    int idx = blockIdx.x * 256 + threadIdx.x;     // (n*NG + g)*HW0 + xy
    int total = N_FR * NG * HW0;
    if (idx >= total) return;
    int xy = idx % HW0;
    int g = (idx / HW0) & (NG - 1);
    int n = idx / (HW0 * NG);
    const float* src = fm0 + ((size_t)(n * C_CH + g * 8)) * HW0 + xy;
    uint4 o;
    o.x = pack2h(src[0],             src[(size_t)HW0]);
    o.y = pack2h(src[2*(size_t)HW0], src[3*(size_t)HW0]);
    o.z = pack2h(src[4*(size_t)HW0], src[5*(size_t)HW0]);
    o.w = pack2h(src[6*(size_t)HW0], src[7*(size_t)HW0]);
    fH[idx] = o;
}

// ---- pool from packed f16: fH -> f1H [N,16,30,40] uint4 ----
__global__ __launch_bounds__(256) void pool_from_fH(const uint4* __restrict__ fH,
                                                    uint4* __restrict__ f1H) {
    int idx = blockIdx.x * 256 + threadIdx.x;     // (n*NG + g)*HW1 + yo*W1 + xo
    int total = N_FR * NG * HW1;
    if (idx >= total) return;
    int xo = idx % W1;
    int yo = (idx / W1) % H1;
    int ng = idx / HW1;
    const uint4* src = fH + ((size_t)ng * H0 + yo * 4) * W0 + xo * 4;
    float s[8];
#pragma unroll
    for (int k = 0; k < 8; ++k) s[k] = 0.f;
#pragma unroll
    for (int yl = 0; yl < 4; ++yl) {
#pragma unroll
        for (int dx = 0; dx < 4; ++dx) {
            Q q; q.u4 = src[(size_t)yl * W0 + dx];
#pragma unroll
            for (int k = 0; k < 4; ++k) {
                s[2*k]   += (float)q.h[k].x;
                s[2*k+1] += (float)q.h[k].y;
            }
        }
    }
    uint4 o;
    o.x = pack2h(s[0] * (1.f/16.f), s[1] * (1.f/16.f));
    o.y = pack2h(s[2] * (1.f/16.f), s[3] * (1.f/16.f));
    o.z = pack2h(s[4] * (1.f/16.f), s[5] * (1.f/16.f));
    o.w = pack2h(s[6] * (1.f/16.f), s[7] * (1.f/16.f));
    f1H[idx] = o;
}

// ---- gmap [M][128][9] fp32 -> gH [M][9][64] u32 (f16 channel pairs) ----
__global__ __launch_bounds__(128) void gpack(const float* __restrict__ g,
                                             unsigned* __restrict__ gH) {
    __shared__ float s[C_CH * 9];
    int m = blockIdx.x;
    const float* src = g + (size_t)m * (C_CH * 9);
    for (int t = threadIdx.x; t < C_CH * 9; t += 128) s[t] = src[t];
    __syncthreads();
    unsigned* dst = gH + (size_t)m * (9 * 64);
    for (int t = threadIdx.x; t < 9 * 64; t += 128) {
        int pq = t >> 6, pr = t & 63;
        dst[t] = pack2h(s[(2 * pr) * 9 + pq], s[(2 * pr + 1) * 9 + pq]);
    }
}

// ---- (frame, y-band) bucket sort ----
__device__ __forceinline__ int sort_key(const int* jj, const float* coords, int e) {
    float cy = coords[(size_t)e * 18 + 1];
    int by0 = (int)floorf(cy) - RADIUS;
    int band = min(max(by0 >> 3, 0), 15);
    return jj[e] * 16 + band;
}

__global__ void zero_kernel(int* cnt) {
    int t = blockIdx.x * blockDim.x + threadIdx.x;
    if (t < 2 * NBKT) cnt[t] = 0;
}

__global__ void hist_kernel(const int* __restrict__ jj, const float* __restrict__ coords,
                            int* __restrict__ cnt, int E) {
    __shared__ int h[NBKT];
    int tid = threadIdx.x;
    h[tid] = 0;
    __syncthreads();
    int e = blockIdx.x * blockDim.x + tid;
    if (e < E) atomicAdd(&h[sort_key(jj, coords, e)], 1);
    __syncthreads();
    if (h[tid] > 0) atomicAdd(&cnt[tid], h[tid]);
}

__global__ void scan_kernel(const int* __restrict__ cnt, int* __restrict__ off) {
    if (threadIdx.x == 0) {
        int s = 0;
        for (int f = 0; f < NBKT; ++f) { off[f] = s; s += cnt[f]; }
    }
}

__global__ void scatter_kernel(const int* __restrict__ jj, const float* __restrict__ coords,
                               int* __restrict__ off, int* __restrict__ perm, int E) {
    __shared__ int h[NBKT];
    __shared__ int base[NBKT];
    int tid = threadIdx.x;
    h[tid] = 0;
    __syncthreads();
    int e = blockIdx.x * blockDim.x + tid;
    int k = 0, rank = 0;
    if (e < E) {
        k = sort_key(jj, coords, e);
        rank = atomicAdd(&h[k], 1);
    }
    __syncthreads();
    if (h[tid] > 0) base[tid] = atomicAdd(&off[tid], h[tid]);
    __syncthreads();
    if (e < E) perm[base[k] + rank] = e;
}

// ---- MFMA corr: one wave per edge. A = window cells x channels (direct global
// gather in fragment layout), B = g-patch channels x pq, C[cell][pq]. ----
__global__ __launch_bounds__(64, 4) void corr_mfma(
        const uint4* __restrict__ fH,    // [N,16,H0,W0] uint4
        const uint4* __restrict__ f1H,   // [N,16,H1,W1] uint4
        const uint4* __restrict__ gH4,   // [M,9,16] uint4
        const float* __restrict__ coords,
        const int* __restrict__ ii,
        const int* __restrict__ jj,
        const int* __restrict__ perm,
        float* __restrict__ out) {
    __shared__ float sC[2 * NCELL * SCSTR];

    int nwg = gridDim.x;
    int q = nwg >> 3, r = nwg & 7;
    int xcd = blockIdx.x & 7;
    int ib = blockIdx.x >> 3;
    int orig = (xcd < r ? xcd * (q + 1) : r * (q + 1) + (xcd - r) * q) + ib;
    int e = perm ? perm[orig] : orig;

    int l = threadIdx.x;
    int lrow = l & 15;        // A row (cell-in-tile) / B col (pq)
    int lk = l >> 4;          // k-chunk 0..3 (8 channels each)

    int iie = __builtin_amdgcn_readfirstlane(ii[e]);
    int jje = __builtin_amdgcn_readfirstlane(jj[e]);
    const float* cb = coords + (size_t)e * 18;

    float cx = cb[0], cy = cb[1];
    int bx0 = (int)floorf(cx) - RADIUS;
    int by0 = (int)floorf(cy) - RADIUS;
    int bx1 = (int)floorf(cx * 0.25f) - RADIUS;
    int by1 = (int)floorf(cy * 0.25f) - RADIUS;

    // per-lane gather offsets for the 7 M-tiles (cells t*16 + lrow)
    int off0[7], off1[7];
#pragma unroll
    for (int t = 0; t < 7; ++t) {
        int c = min(t * 16 + lrow, NCELL - 1);
        int iy = c / EXT, ix = c - iy * EXT;
        int gy0 = min(max(by0 + iy, 0), H0 - 1);
        int gx0 = min(max(bx0 + ix, 0), W0 - 1);
        int gy1 = min(max(by1 + iy, 0), H1 - 1);
        int gx1 = min(max(bx1 + ix, 0), W1 - 1);
        off0[t] = gy0 * W0 + gx0;
        off1[t] = gy1 * W1 + gx1;
    }

    const uint4* f0 = fH + (size_t)jje * NG * HW0;
    const uint4* f1 = f1H + (size_t)jje * NG * HW1;
    int pqc = min(lrow, 8);
    const uint4* gb = gH4 + (size_t)iie * 144 + pqc * 16 + lk;

    f32x4 acc0[7], acc1[7];
#pragma unroll
    for (int t = 0; t < 7; ++t) {
        acc0[t] = (f32x4){0.f, 0.f, 0.f, 0.f};
        acc1[t] = (f32x4){0.f, 0.f, 0.f, 0.f};
    }

#pragma unroll
    for (int kk = 0; kk < 4; ++kk) {
        AB b; b.u4 = gb[kk * 4];
        const uint4* p0 = f0 + (size_t)(kk * 4 + lk) * HW0;
        const uint4* p1 = f1 + (size_t)(kk * 4 + lk) * HW1;
        AB a[7];
#pragma unroll
        for (int t = 0; t < 7; ++t) a[t].u4 = p0[off0[t]];
#pragma unroll
        for (int t = 0; t < 7; ++t)
            acc0[t] = __builtin_amdgcn_mfma_f32_16x16x32_f16(a[t].h8, b.h8, acc0[t], 0, 0, 0);
#pragma unroll
        for (int t = 0; t < 7; ++t) a[t].u4 = p1[off1[t]];
#pragma unroll
        for (int t = 0; t < 7; ++t)
            acc1[t] = __builtin_amdgcn_mfma_f32_16x16x32_f16(a[t].h8, b.h8, acc1[t], 0, 0, 0);
    }

    // C layout: col = l&15 (pq), row = (l>>4)*4 + reg (cell-in-tile)
    if (lrow < 9) {
#pragma unroll
        for (int t = 0; t < 7; ++t) {
#pragma unroll
            for (int r2 = 0; r2 < 4; ++r2) {
                int cell = t * 16 + lk * 4 + r2;
                if (cell < NCELL) {
                    sC[cell * SCSTR + lrow] = acc0[t][r2];
                    sC[NCELL * SCSTR + cell * SCSTR + lrow] = acc1[t][r2];
                }
            }
        }
    }
    __syncthreads();

    for (int o = l; o < 882; o += 64) {
        int lvl = o & 1;
        int rr = o >> 1;          // (a*7+b)*9 + pq
        int pq = rr % 9;
        int ab = rr / 9;
        int a = ab / 7, b = ab - a * 7;
        float s = lvl ? 0.25f : 1.f;
        float x = cb[pq * 2 + 0] * s;
        float y = cb[pq * 2 + 1] * s;
        float x0f = floorf(x), y0f = floorf(y);
        float fx = x - x0f, fy = y - y0f;
        int offx = (int)x0f - RADIUS - (lvl ? bx1 : bx0);
        int offy = (int)y0f - RADIUS - (lvl ? by1 : by0);
        int cell2 = (offy + a) * EXT + (offx + b);
        int base = lvl * (NCELL * SCSTR) + cell2 * SCSTR + pq;
        float c00 = sC[base];
        float c01 = sC[base + SCSTR];
        float c10 = sC[base + EXT * SCSTR];
        float c11 = sC[base + EXT * SCSTR + SCSTR];
        float v = (1.f - fy) * (1.f - fx) * c00 + (1.f - fy) * fx * c01
                + fy * (1.f - fx) * c10 + fy * fx * c11;
        out[(size_t)e * 882 + (size_t)rr * 2 + lvl] = v;
    }
}

// ---- fp32 fallback (small ws) ----
__global__ __launch_bounds__(256) void pool_fm1T(const float* __restrict__ fm0,
                                                 float* __restrict__ fm1T) {
    __shared__ float s[C_CH * 41];
    int blk = blockIdx.x;
    int yo = blk % H1;
    int n = blk / H1;
    for (int pair = threadIdx.x; pair < C_CH * W1; pair += 256) {
        int c = pair / W1, xo = pair - c * W1;
        const float* p = fm0 + (((size_t)(n * C_CH + c) * H0) + yo * 4) * W0 + xo * 4;
        float sum = 0.f;
#pragma unroll
        for (int yl = 0; yl < 4; ++yl) {
            float4 v = *reinterpret_cast<const float4*>(p + yl * W0);
            sum += v.x + v.y + v.z + v.w;
        }
        s[c * 41 + xo] = sum * (1.f / 16.f);
    }
    __syncthreads();
    float* dp = fm1T + (size_t)blk * W1 * C_CH;
    for (int t = threadIdx.x; t < W1 * C_CH; t += 256) {
        int xo = t >> 7, c = t & 127;
        dp[t] = s[c * 41 + xo];
    }
}

__global__ __launch_bounds__(128) void corr_kernel(
        const float* __restrict__ fmap, const float* __restrict__ fm1T,
        const float* __restrict__ gmap, const float* __restrict__ coords,
        const int* __restrict__ ii, const int* __restrict__ jj,
        float* __restrict__ out) {
    __shared__ float sC[2 * NCELL * SCSTR];
    int e = blockIdx.x;
    int tid = threadIdx.x;
    int iie = __builtin_amdgcn_readfirstlane(ii[e]);
    int jje = __builtin_amdgcn_readfirstlane(jj[e]);
    const float* cb = coords + (size_t)e * 18;
    float cx = cb[0], cy = cb[1];
    int bx0 = (int)floorf(cx) - RADIUS;
    int by0 = (int)floorf(cy) - RADIUS;
    int bx1 = (int)floorf(cx * 0.25f) - RADIUS;
    int by1 = (int)floorf(cy * 0.25f) - RADIUS;
    int cell = min(tid, NCELL - 1);
    int iy = cell / EXT, ix = cell - iy * EXT;
    int gy0 = min(max(by0 + iy, 0), H0 - 1);
    int gx0 = min(max(bx0 + ix, 0), W0 - 1);
    int gy1 = min(max(by1 + iy, 0), H1 - 1);
    int gx1 = min(max(bx1 + ix, 0), W1 - 1);
    const float* fp0 = fmap + (size_t)jje * C_CH * HW0 + gy0 * W0 + gx0;
    const float* fp1 = fm1T + (((size_t)jje * H1 + gy1) * W1 + gx1) * C_CH;
    float acc0[9], acc1[9];
#pragma unroll
    for (int pq = 0; pq < 9; ++pq) { acc0[pq] = 0.f; acc1[pq] = 0.f; }
    const float* gp = gmap + (size_t)iie * (C_CH * 9);
#pragma unroll 2
    for (int c = 0; c < C_CH; c += 4) {
        float f0 = fp0[(size_t)(c + 0) * HW0];
        float f1 = fp0[(size_t)(c + 1) * HW0];
        float f2 = fp0[(size_t)(c + 2) * HW0];
        float f3 = fp0[(size_t)(c + 3) * HW0];
        float4 fv = *reinterpret_cast<const float4*>(fp1 + c);
#pragma unroll
        for (int pq = 0; pq < 9; ++pq) {
            float g0 = gp[(c + 0) * 9 + pq];
            float g1 = gp[(c + 1) * 9 + pq];
            float g2 = gp[(c + 2) * 9 + pq];
            float g3 = gp[(c + 3) * 9 + pq];
            acc0[pq] += f0 * g0 + f1 * g1 + f2 * g2 + f3 * g3;
            acc1[pq] += fv.x * g0 + fv.y * g1 + fv.z * g2 + fv.w * g3;
        }
    }
    if (tid < NCELL) {
        float* s0 = &sC[cell * SCSTR];
        float* s1 = &sC[NCELL * SCSTR + cell * SCSTR];
        *reinterpret_cast<float4*>(s0)     = float4{acc0[0], acc0[1], acc0[2], acc0[3]};
        *reinterpret_cast<float4*>(s0 + 4) = float4{acc0[4], acc0[5], acc0[6], acc0[7]};
        s0[8] = acc0[8];
        *reinterpret_cast<float4*>(s1)     = float4{acc1[0], acc1[1], acc1[2], acc1[3]};
        *reinterpret_cast<float4*>(s1 + 4) = float4{acc1[4], acc1[5], acc1[6], acc1[7]};
        s1[8] = acc1[8];
    }
    __syncthreads();
    for (int o = tid; o < 882; o += 128) {
        int lvl = o & 1;
        int rr = o >> 1;
        int pq = rr % 9;
        int ab = rr / 9;
        int a = ab / 7, b = ab - a * 7;
        float s = lvl ? 0.25f : 1.f;
        float x = cb[pq * 2 + 0] * s;
        float y = cb[pq * 2 + 1] * s;
        float x0f = floorf(x), y0f = floorf(y);
        float fx = x - x0f, fy = y - y0f;
        int offx = (int)x0f - RADIUS - (lvl ? bx1 : bx0);
        int offy = (int)y0f - RADIUS - (lvl ? by1 : by0);
        int cell2 = (offy + a) * EXT + (offx + b);
        int base = lvl * (NCELL * SCSTR) + cell2 * SCSTR + pq;
        float c00 = sC[base];
        float c01 = sC[base + SCSTR];
        float c10 = sC[base + EXT * SCSTR];
        float c11 = sC[base + EXT * SCSTR + SCSTR];
        float v = (1.f - fy) * (1.f - fx) * c00 + (1.f - fy) * fx * c01
                + fy * (1.f - fx) * c10 + fy * fx * c11;
        out[(size_t)e * 882 + (size_t)rr * 2 + lvl] = v;
    }
}

extern "C" void kernel_launch(void* const* d_in, const int* in_sizes, int n_in,
                              void* d_out, int out_size, void* d_ws, size_t ws_size,
                              hipStream_t stream) {
    const float* fmap   = (const float*)d_in[0];
    const float* gmap   = (const float*)d_in[1];
    const float* coords = (const float*)d_in[2];
    const int* ii       = (const int*)d_in[3];
    const int* jj       = (const int*)d_in[4];
    float* out = (float*)d_out;
    int E = in_sizes[3];

    size_t szFH  = (size_t)N_FR * C_CH * HW0 * 2;       // 78.6 MB
    size_t szF1H = (size_t)N_FR * C_CH * HW1 * 2;       // 4.9 MB
    size_t szGH  = (size_t)M_PT * 9 * C_CH * 2 + 4096;  // 3.5 MB (+pad)
    size_t need_h = szFH + szF1H + szGH + 2048 + (size_t)E * 4;

    if (ws_size >= need_h) {
        uint4* fH  = (uint4*)d_ws;
        uint4* f1H = (uint4*)((char*)d_ws + szFH);
        unsigned* gH = (unsigned*)((char*)d_ws + szFH + szF1H);
        int* cnt  = (int*)((char*)d_ws + szFH + szF1H + szGH);
        int* off  = cnt + NBKT;
        int* perm = off + NBKT;

        int tot_pack = N_FR * NG * HW0;
        pack_fmap2<<<(tot_pack + 255) / 256, 256, 0, stream>>>(fmap, fH);
        int tot_pool = N_FR * NG * HW1;
        pool_from_fH<<<(tot_pool + 255) / 256, 256, 0, stream>>>(fH, f1H);
        gpack<<<M_PT, 128, 0, stream>>>(gmap, gH);

        int nb = (E + NBKT - 1) / NBKT;
        zero_kernel<<<(2 * NBKT + 255) / 256, 256, 0, stream>>>(cnt);
        hist_kernel<<<nb, NBKT, 0, stream>>>(jj, coords, cnt, E);
        scan_kernel<<<1, 64, 0, stream>>>(cnt, off);
        scatter_kernel<<<nb, NBKT, 0, stream>>>(jj, coords, off, perm, E);

        corr_mfma<<<E, 64, 0, stream>>>(fH, f1H, (const uint4*)gH,
                                        coords, ii, jj, perm, out);
        return;
    }

    // ---- fp32 fallback ----
    float* fm1T = (float*)d_ws;
    pool_fm1T<<<N_FR * H1, 256, 0, stream>>>(fmap, fm1T);
    corr_kernel<<<E, 128, 0, stream>>>(fmap, fm1T, gmap, coords, ii, jj, out);
}

// Round 11
// 101.773 us; speedup vs baseline: 4.7771x; 1.1134x over previous
//
#include <hip/hip_runtime.h>

#define RADIUS 3
#define C_CH 128
#define NG 16               // channel groups of 8
#define N_FR 16
#define H0 120
#define W0 160
#define HW0 (H0*W0)
#define H1 30
#define W1 40
#define HW1 (H1*W1)
#define EXT 10
#define NCELL 100
#define M_PT 1536
#define SCSTR 12
#define NBKT 256

typedef _Float16 half2v __attribute__((ext_vector_type(2)));
typedef _Float16 f16x8 __attribute__((ext_vector_type(8)));
typedef float f32x4 __attribute__((ext_vector_type(4)));
union Q { uint4 u4; half2v h[4]; };
union AB { uint4 u4; f16x8 h8; };

__device__ __forceinline__ unsigned pack2h(float a, float b) {
    union { _Float16 h[2]; unsigned u; } x;
    x.h[0] = (_Float16)a; x.h[1] = (_Float16)b;
    return x.u;
}

// ---- fused pack+pool: fmap [N,C,120,160] fp32 -> fH [N,16,120,160]u4 + f1H [N,16,30,40]u4 ----
// block = one (n, g, 4-row strip): packs 640 uint4 (also to LDS), then pools 40 outputs.
__global__ __launch_bounds__(256) void pack_pool(const float* __restrict__ fm0,
                                                 uint4* __restrict__ fH,
                                                 uint4* __restrict__ f1H) {
    __shared__ uint4 s[4][W0];          // 10240 B
    int blk = blockIdx.x;               // (n*NG + g)*H1 + yo
    int yo = blk % H1;
    int ng = blk / H1;
    int g = ng & (NG - 1);
    int n = ng / NG;
    int y0 = yo * 4;
    const float* src0 = fm0 + ((size_t)(n * C_CH + g * 8)) * HW0;
    uint4* dst = fH + ((size_t)ng * H0 + y0) * W0;

    for (int t = threadIdx.x; t < 4 * W0; t += 256) {
        int yl = t / W0, x = t - yl * W0;
        const float* src = src0 + (size_t)(y0 + yl) * W0 + x;
        uint4 o;
        o.x = pack2h(src[0],             src[(size_t)HW0]);
        o.y = pack2h(src[2*(size_t)HW0], src[3*(size_t)HW0]);
        o.z = pack2h(src[4*(size_t)HW0], src[5*(size_t)HW0]);
        o.w = pack2h(src[6*(size_t)HW0], src[7*(size_t)HW0]);
        s[yl][x] = o;
        dst[t] = o;
    }
    __syncthreads();

    if (threadIdx.x < W1) {
        int xo = threadIdx.x;
        float sm[8];
#pragma unroll
        for (int k = 0; k < 8; ++k) sm[k] = 0.f;
#pragma unroll
        for (int yl = 0; yl < 4; ++yl) {
#pragma unroll
            for (int dx = 0; dx < 4; ++dx) {
                Q qv; qv.u4 = s[yl][xo * 4 + dx];
#pragma unroll
                for (int k = 0; k < 4; ++k) {
                    sm[2*k]   += (float)qv.h[k].x;
                    sm[2*k+1] += (float)qv.h[k].y;
                }
            }
        }
        uint4 o;
        o.x = pack2h(sm[0] * (1.f/16.f), sm[1] * (1.f/16.f));
        o.y = pack2h(sm[2] * (1.f/16.f), sm[3] * (1.f/16.f));
        o.z = pack2h(sm[4] * (1.f/16.f), sm[5] * (1.f/16.f));
        o.w = pack2h(sm[6] * (1.f/16.f), sm[7] * (1.f/16.f));
        f1H[(size_t)ng * HW1 + yo * W1 + xo] = o;
    }
}

// ---- gmap [M][128][9] fp32 -> gH [M][9][64] u32 (f16 channel pairs) ----
__global__ __launch_bounds__(128) void gpack(const float* __restrict__ g,
                                             unsigned* __restrict__ gH) {
    __shared__ float s[C_CH * 9];
    int m = blockIdx.x;
    const float* src = g + (size_t)m * (C_CH * 9);
    for (int t = threadIdx.x; t < C_CH * 9; t += 128) s[t] = src[t];
    __syncthreads();
    unsigned* dst = gH + (size_t)m * (9 * 64);
    for (int t = threadIdx.x; t < 9 * 64; t += 128) {
        int pq = t >> 6, pr = t & 63;
        dst[t] = pack2h(s[(2 * pr) * 9 + pq], s[(2 * pr + 1) * 9 + pq]);
    }
}

// ---- (frame, y-band) bucket sort ----
__device__ __forceinline__ int sort_key(const int* jj, const float* coords, int e) {
    float cy = coords[(size_t)e * 18 + 1];
    int by0 = (int)floorf(cy) - RADIUS;
    int band = min(max(by0 >> 3, 0), 15);
    return jj[e] * 16 + band;
}

__global__ void hist_kernel(const int* __restrict__ jj, const float* __restrict__ coords,
                            int* __restrict__ cnt, int E) {
    __shared__ int h[NBKT];
    int tid = threadIdx.x;
    h[tid] = 0;
    __syncthreads();
    int e = blockIdx.x * blockDim.x + tid;
    if (e < E) atomicAdd(&h[sort_key(jj, coords, e)], 1);
    __syncthreads();
    if (h[tid] > 0) atomicAdd(&cnt[tid], h[tid]);
}

__global__ void scan_kernel(const int* __restrict__ cnt, int* __restrict__ off) {
    if (threadIdx.x == 0) {
        int s = 0;
        for (int f = 0; f < NBKT; ++f) { off[f] = s; s += cnt[f]; }
    }
}

__global__ void scatter_kernel(const int* __restrict__ jj, const float* __restrict__ coords,
                               int* __restrict__ off, int* __restrict__ perm, int E) {
    __shared__ int h[NBKT];
    __shared__ int base[NBKT];
    int tid = threadIdx.x;
    h[tid] = 0;
    __syncthreads();
    int e = blockIdx.x * blockDim.x + tid;
    int k = 0, rank = 0;
    if (e < E) {
        k = sort_key(jj, coords, e);
        rank = atomicAdd(&h[k], 1);
    }
    __syncthreads();
    if (h[tid] > 0) base[tid] = atomicAdd(&off[tid], h[tid]);
    __syncthreads();
    if (e < E) perm[base[k] + rank] = e;
}

// ---- MFMA corr: one wave per edge (unchanged from R10) ----
__global__ __launch_bounds__(64, 4) void corr_mfma(
        const uint4* __restrict__ fH,    // [N,16,H0,W0] uint4
        const uint4* __restrict__ f1H,   // [N,16,H1,W1] uint4
        const uint4* __restrict__ gH4,   // [M,9,16] uint4
        const float* __restrict__ coords,
        const int* __restrict__ ii,
        const int* __restrict__ jj,
        const int* __restrict__ perm,
        float* __restrict__ out) {
    __shared__ float sC[2 * NCELL * SCSTR];

    int nwg = gridDim.x;
    int q = nwg >> 3, r = nwg & 7;
    int xcd = blockIdx.x & 7;
    int ib = blockIdx.x >> 3;
    int orig = (xcd < r ? xcd * (q + 1) : r * (q + 1) + (xcd - r) * q) + ib;
    int e = perm ? perm[orig] : orig;

    int l = threadIdx.x;
    int lrow = l & 15;        // A row (cell-in-tile) / B col (pq)
    int lk = l >> 4;          // k-chunk 0..3 (8 channels each)

    int iie = __builtin_amdgcn_readfirstlane(ii[e]);
    int jje = __builtin_amdgcn_readfirstlane(jj[e]);
    const float* cb = coords + (size_t)e * 18;

    float cx = cb[0], cy = cb[1];
    int bx0 = (int)floorf(cx) - RADIUS;
    int by0 = (int)floorf(cy) - RADIUS;
    int bx1 = (int)floorf(cx * 0.25f) - RADIUS;
    int by1 = (int)floorf(cy * 0.25f) - RADIUS;

    int off0[7], off1[7];
#pragma unroll
    for (int t = 0; t < 7; ++t) {
        int c = min(t * 16 + lrow, NCELL - 1);
        int iy = c / EXT, ix = c - iy * EXT;
        int gy0 = min(max(by0 + iy, 0), H0 - 1);
        int gx0 = min(max(bx0 + ix, 0), W0 - 1);
        int gy1 = min(max(by1 + iy, 0), H1 - 1);
        int gx1 = min(max(bx1 + ix, 0), W1 - 1);
        off0[t] = gy0 * W0 + gx0;
        off1[t] = gy1 * W1 + gx1;
    }

    const uint4* f0 = fH + (size_t)jje * NG * HW0;
    const uint4* f1 = f1H + (size_t)jje * NG * HW1;
    int pqc = min(lrow, 8);
    const uint4* gb = gH4 + (size_t)iie * 144 + pqc * 16 + lk;

    f32x4 acc0[7], acc1[7];
#pragma unroll
    for (int t = 0; t < 7; ++t) {
        acc0[t] = (f32x4){0.f, 0.f, 0.f, 0.f};
        acc1[t] = (f32x4){0.f, 0.f, 0.f, 0.f};
    }

#pragma unroll
    for (int kk = 0; kk < 4; ++kk) {
        AB b; b.u4 = gb[kk * 4];
        const uint4* p0 = f0 + (size_t)(kk * 4 + lk) * HW0;
        const uint4* p1 = f1 + (size_t)(kk * 4 + lk) * HW1;
        AB a[7];
#pragma unroll
        for (int t = 0; t < 7; ++t) a[t].u4 = p0[off0[t]];
#pragma unroll
        for (int t = 0; t < 7; ++t)
            acc0[t] = __builtin_amdgcn_mfma_f32_16x16x32_f16(a[t].h8, b.h8, acc0[t], 0, 0, 0);
#pragma unroll
        for (int t = 0; t < 7; ++t) a[t].u4 = p1[off1[t]];
#pragma unroll
        for (int t = 0; t < 7; ++t)
            acc1[t] = __builtin_amdgcn_mfma_f32_16x16x32_f16(a[t].h8, b.h8, acc1[t], 0, 0, 0);
    }

    if (lrow < 9) {
#pragma unroll
        for (int t = 0; t < 7; ++t) {
#pragma unroll
            for (int r2 = 0; r2 < 4; ++r2) {
                int cell = t * 16 + lk * 4 + r2;
                if (cell < NCELL) {
                    sC[cell * SCSTR + lrow] = acc0[t][r2];
                    sC[NCELL * SCSTR + cell * SCSTR + lrow] = acc1[t][r2];
                }
            }
        }
    }
    __syncthreads();

    for (int o = l; o < 882; o += 64) {
        int lvl = o & 1;
        int rr = o >> 1;          // (a*7+b)*9 + pq
        int pq = rr % 9;
        int ab = rr / 9;
        int a = ab / 7, b = ab - a * 7;
        float s = lvl ? 0.25f : 1.f;
        float x = cb[pq * 2 + 0] * s;
        float y = cb[pq * 2 + 1] * s;
        float x0f = floorf(x), y0f = floorf(y);
        float fx = x - x0f, fy = y - y0f;
        int offx = (int)x0f - RADIUS - (lvl ? bx1 : bx0);
        int offy = (int)y0f - RADIUS - (lvl ? by1 : by0);
        int cell2 = (offy + a) * EXT + (offx + b);
        int base = lvl * (NCELL * SCSTR) + cell2 * SCSTR + pq;
        float c00 = sC[base];
        float c01 = sC[base + SCSTR];
        float c10 = sC[base + EXT * SCSTR];
        float c11 = sC[base + EXT * SCSTR + SCSTR];
        float v = (1.f - fy) * (1.f - fx) * c00 + (1.f - fy) * fx * c01
                + fy * (1.f - fx) * c10 + fy * fx * c11;
        out[(size_t)e * 882 + (size_t)rr * 2 + lvl] = v;
    }
}

// ---- fp32 fallback (small ws) ----
__global__ __launch_bounds__(256) void pool_fm1T(const float* __restrict__ fm0,
                                                 float* __restrict__ fm1T) {
    __shared__ float s[C_CH * 41];
    int blk = blockIdx.x;
    int yo = blk % H1;
    int n = blk / H1;
    for (int pair = threadIdx.x; pair < C_CH * W1; pair += 256) {
        int c = pair / W1, xo = pair - c * W1;
        const float* p = fm0 + (((size_t)(n * C_CH + c) * H0) + yo * 4) * W0 + xo * 4;
        float sum = 0.f;
#pragma unroll
        for (int yl = 0; yl < 4; ++yl) {
            float4 v = *reinterpret_cast<const float4*>(p + yl * W0);
            sum += v.x + v.y + v.z + v.w;
        }
        s[c * 41 + xo] = sum * (1.f / 16.f);
    }
    __syncthreads();
    float* dp = fm1T + (size_t)blk * W1 * C_CH;
    for (int t = threadIdx.x; t < W1 * C_CH; t += 256) {
        int xo = t >> 7, c = t & 127;
        dp[t] = s[c * 41 + xo];
    }
}

__global__ __launch_bounds__(128) void corr_kernel(
        const float* __restrict__ fmap, const float* __restrict__ fm1T,
        const float* __restrict__ gmap, const float* __restrict__ coords,
        const int* __restrict__ ii, const int* __restrict__ jj,
        float* __restrict__ out) {
    __shared__ float sC[2 * NCELL * SCSTR];
    int e = blockIdx.x;
    int tid = threadIdx.x;
    int iie = __builtin_amdgcn_readfirstlane(ii[e]);
    int jje = __builtin_amdgcn_readfirstlane(jj[e]);
    const float* cb = coords + (size_t)e * 18;
    float cx = cb[0], cy = cb[1];
    int bx0 = (int)floorf(cx) - RADIUS;
    int by0 = (int)floorf(cy) - RADIUS;
    int bx1 = (int)floorf(cx * 0.25f) - RADIUS;
    int by1 = (int)floorf(cy * 0.25f) - RADIUS;
    int cell = min(tid, NCELL - 1);
    int iy = cell / EXT, ix = cell - iy * EXT;
    int gy0 = min(max(by0 + iy, 0), H0 - 1);
    int gx0 = min(max(bx0 + ix, 0), W0 - 1);
    int gy1 = min(max(by1 + iy, 0), H1 - 1);
    int gx1 = min(max(bx1 + ix, 0), W1 - 1);
    const float* fp0 = fmap + (size_t)jje * C_CH * HW0 + gy0 * W0 + gx0;
    const float* fp1 = fm1T + (((size_t)jje * H1 + gy1) * W1 + gx1) * C_CH;
    float acc0[9], acc1[9];
#pragma unroll
    for (int pq = 0; pq < 9; ++pq) { acc0[pq] = 0.f; acc1[pq] = 0.f; }
    const float* gp = gmap + (size_t)iie * (C_CH * 9);
#pragma unroll 2
    for (int c = 0; c < C_CH; c += 4) {
        float f0 = fp0[(size_t)(c + 0) * HW0];
        float f1 = fp0[(size_t)(c + 1) * HW0];
        float f2 = fp0[(size_t)(c + 2) * HW0];
        float f3 = fp0[(size_t)(c + 3) * HW0];
        float4 fv = *reinterpret_cast<const float4*>(fp1 + c);
#pragma unroll
        for (int pq = 0; pq < 9; ++pq) {
            float g0 = gp[(c + 0) * 9 + pq];
            float g1 = gp[(c + 1) * 9 + pq];
            float g2 = gp[(c + 2) * 9 + pq];
            float g3 = gp[(c + 3) * 9 + pq];
            acc0[pq] += f0 * g0 + f1 * g1 + f2 * g2 + f3 * g3;
            acc1[pq] += fv.x * g0 + fv.y * g1 + fv.z * g2 + fv.w * g3;
        }
    }
    if (tid < NCELL) {
        float* s0 = &sC[cell * SCSTR];
        float* s1 = &sC[NCELL * SCSTR + cell * SCSTR];
        *reinterpret_cast<float4*>(s0)     = float4{acc0[0], acc0[1], acc0[2], acc0[3]};
        *reinterpret_cast<float4*>(s0 + 4) = float4{acc0[4], acc0[5], acc0[6], acc0[7]};
        s0[8] = acc0[8];
        *reinterpret_cast<float4*>(s1)     = float4{acc1[0], acc1[1], acc1[2], acc1[3]};
        *reinterpret_cast<float4*>(s1 + 4) = float4{acc1[4], acc1[5], acc1[6], acc1[7]};
        s1[8] = acc1[8];
    }
    __syncthreads();
    for (int o = tid; o < 882; o += 128) {
        int lvl = o & 1;
        int rr = o >> 1;
        int pq = rr % 9;
        int ab = rr / 9;
        int a = ab / 7, b = ab - a * 7;
        float s = lvl ? 0.25f : 1.f;
        float x = cb[pq * 2 + 0] * s;
        float y = cb[pq * 2 + 1] * s;
        float x0f = floorf(x), y0f = floorf(y);
        float fx = x - x0f, fy = y - y0f;
        int offx = (int)x0f - RADIUS - (lvl ? bx1 : bx0);
        int offy = (int)y0f - RADIUS - (lvl ? by1 : by0);
        int cell2 = (offy + a) * EXT + (offx + b);
        int base = lvl * (NCELL * SCSTR) + cell2 * SCSTR + pq;
        float c00 = sC[base];
        float c01 = sC[base + SCSTR];
        float c10 = sC[base + EXT * SCSTR];
        float c11 = sC[base + EXT * SCSTR + SCSTR];
        float v = (1.f - fy) * (1.f - fx) * c00 + (1.f - fy) * fx * c01
                + fy * (1.f - fx) * c10 + fy * fx * c11;
        out[(size_t)e * 882 + (size_t)rr * 2 + lvl] = v;
    }
}

extern "C" void kernel_launch(void* const* d_in, const int* in_sizes, int n_in,
                              void* d_out, int out_size, void* d_ws, size_t ws_size,
                              hipStream_t stream) {
    const float* fmap   = (const float*)d_in[0];
    const float* gmap   = (const float*)d_in[1];
    const float* coords = (const float*)d_in[2];
    const int* ii       = (const int*)d_in[3];
    const int* jj       = (const int*)d_in[4];
    float* out = (float*)d_out;
    int E = in_sizes[3];

    size_t szFH  = (size_t)N_FR * C_CH * HW0 * 2;       // 78.6 MB
    size_t szF1H = (size_t)N_FR * C_CH * HW1 * 2;       // 4.9 MB
    size_t szGH  = (size_t)M_PT * 9 * C_CH * 2 + 4096;  // 3.5 MB (+pad)
    size_t need_h = szFH + szF1H + szGH + 2048 + (size_t)E * 4;

    if (ws_size >= need_h) {
        uint4* fH  = (uint4*)d_ws;
        uint4* f1H = (uint4*)((char*)d_ws + szFH);
        unsigned* gH = (unsigned*)((char*)d_ws + szFH + szF1H);
        int* cnt  = (int*)((char*)d_ws + szFH + szF1H + szGH);
        int* off  = cnt + NBKT;
        int* perm = off + NBKT;

        pack_pool<<<N_FR * NG * H1, 256, 0, stream>>>(fmap, fH, f1H);
        gpack<<<M_PT, 128, 0, stream>>>(gmap, gH);

        hipMemsetAsync(cnt, 0, 2 * NBKT * sizeof(int), stream);
        int nb = (E + NBKT - 1) / NBKT;
        hist_kernel<<<nb, NBKT, 0, stream>>>(jj, coords, cnt, E);
        scan_kernel<<<1, 64, 0, stream>>>(cnt, off);
        scatter_kernel<<<nb, NBKT, 0, stream>>>(jj, coords, off, perm, E);

        corr_mfma<<<E, 64, 0, stream>>>(fH, f1H, (const uint4*)gH,
                                        coords, ii, jj, perm, out);
        return;
    }

    // ---- fp32 fallback ----
    float* fm1T = (float*)d_ws;
    pool_fm1T<<<N_FR * H1, 256, 0, stream>>>(fmap, fm1T);
    corr_kernel<<<E, 128, 0, stream>>>(fmap, fm1T, gmap, coords, ii, jj, out);
}

// Round 12
// 99.137 us; speedup vs baseline: 4.9041x; 1.0266x over previous
//
#include <hip/hip_runtime.h>

#define RADIUS 3
#define C_CH 128
#define NG 16               // channel groups of 8
#define N_FR 16
#define H0 120
#define W0 160
#define HW0 (H0*W0)
#define H1 30
#define W1 40
#define HW1 (H1*W1)
#define EXT 10
#define NCELL 100
#define M_PT 1536
#define SCSTR 12
#define NBKT 256

typedef _Float16 half2v __attribute__((ext_vector_type(2)));
typedef _Float16 f16x8 __attribute__((ext_vector_type(8)));
typedef float f32x4 __attribute__((ext_vector_type(4)));
union Q { uint4 u4; half2v h[4]; };
union AB { uint4 u4; f16x8 h8; };

__device__ __forceinline__ unsigned pack2h(float a, float b) {
    union { _Float16 h[2]; unsigned u; } x;
    x.h[0] = (_Float16)a; x.h[1] = (_Float16)b;
    return x.u;
}

// ---- fused pack+pool: fmap [N,C,120,160] fp32 -> fH [N,16,120,160]u4 + f1H [N,16,30,40]u4 ----
__global__ __launch_bounds__(256) void pack_pool(const float* __restrict__ fm0,
                                                 uint4* __restrict__ fH,
                                                 uint4* __restrict__ f1H) {
    __shared__ uint4 s[4][W0];          // 10240 B
    int blk = blockIdx.x;               // (n*NG + g)*H1 + yo
    int yo = blk % H1;
    int ng = blk / H1;
    int g = ng & (NG - 1);
    int n = ng / NG;
    int y0 = yo * 4;
    const float* src0 = fm0 + ((size_t)(n * C_CH + g * 8)) * HW0;
    uint4* dst = fH + ((size_t)ng * H0 + y0) * W0;

    for (int t = threadIdx.x; t < 4 * W0; t += 256) {
        int yl = t / W0, x = t - yl * W0;
        const float* src = src0 + (size_t)(y0 + yl) * W0 + x;
        uint4 o;
        o.x = pack2h(src[0],             src[(size_t)HW0]);
        o.y = pack2h(src[2*(size_t)HW0], src[3*(size_t)HW0]);
        o.z = pack2h(src[4*(size_t)HW0], src[5*(size_t)HW0]);
        o.w = pack2h(src[6*(size_t)HW0], src[7*(size_t)HW0]);
        s[yl][x] = o;
        dst[t] = o;
    }
    __syncthreads();

    if (threadIdx.x < W1) {
        int xo = threadIdx.x;
        float sm[8];
#pragma unroll
        for (int k = 0; k < 8; ++k) sm[k] = 0.f;
#pragma unroll
        for (int yl = 0; yl < 4; ++yl) {
#pragma unroll
            for (int dx = 0; dx < 4; ++dx) {
                Q qv; qv.u4 = s[yl][xo * 4 + dx];
#pragma unroll
                for (int k = 0; k < 4; ++k) {
                    sm[2*k]   += (float)qv.h[k].x;
                    sm[2*k+1] += (float)qv.h[k].y;
                }
            }
        }
        uint4 o;
        o.x = pack2h(sm[0] * (1.f/16.f), sm[1] * (1.f/16.f));
        o.y = pack2h(sm[2] * (1.f/16.f), sm[3] * (1.f/16.f));
        o.z = pack2h(sm[4] * (1.f/16.f), sm[5] * (1.f/16.f));
        o.w = pack2h(sm[6] * (1.f/16.f), sm[7] * (1.f/16.f));
        f1H[(size_t)ng * HW1 + yo * W1 + xo] = o;
    }
}

// ---- gmap [M][128][9] fp32 -> gH [M][9][64] u32 (f16 channel pairs) ----
__global__ __launch_bounds__(128) void gpack(const float* __restrict__ g,
                                             unsigned* __restrict__ gH) {
    __shared__ float s[C_CH * 9];
    int m = blockIdx.x;
    const float* src = g + (size_t)m * (C_CH * 9);
    for (int t = threadIdx.x; t < C_CH * 9; t += 128) s[t] = src[t];
    __syncthreads();
    unsigned* dst = gH + (size_t)m * (9 * 64);
    for (int t = threadIdx.x; t < 9 * 64; t += 128) {
        int pq = t >> 6, pr = t & 63;
        dst[t] = pack2h(s[(2 * pr) * 9 + pq], s[(2 * pr + 1) * 9 + pq]);
    }
}

// ---- (frame, y-band) bucket sort ----
__device__ __forceinline__ int sort_key(const int* jj, const float* coords, int e) {
    float cy = coords[(size_t)e * 18 + 1];
    int by0 = (int)floorf(cy) - RADIUS;
    int band = min(max(by0 >> 3, 0), 15);
    return jj[e] * 16 + band;
}

__global__ void hist_kernel(const int* __restrict__ jj, const float* __restrict__ coords,
                            int* __restrict__ cnt, int E) {
    __shared__ int h[NBKT];
    int tid = threadIdx.x;
    h[tid] = 0;
    __syncthreads();
    int e = blockIdx.x * blockDim.x + tid;
    if (e < E) atomicAdd(&h[sort_key(jj, coords, e)], 1);
    __syncthreads();
    if (h[tid] > 0) atomicAdd(&cnt[tid], h[tid]);
}

__global__ void scan_kernel(const int* __restrict__ cnt, int* __restrict__ off) {
    if (threadIdx.x == 0) {
        int s = 0;
        for (int f = 0; f < NBKT; ++f) { off[f] = s; s += cnt[f]; }
    }
}

__global__ void scatter_kernel(const int* __restrict__ jj, const float* __restrict__ coords,
                               int* __restrict__ off, int* __restrict__ perm, int E) {
    __shared__ int h[NBKT];
    __shared__ int base[NBKT];
    int tid = threadIdx.x;
    h[tid] = 0;
    __syncthreads();
    int e = blockIdx.x * blockDim.x + tid;
    int k = 0, rank = 0;
    if (e < E) {
        k = sort_key(jj, coords, e);
        rank = atomicAdd(&h[k], 1);
    }
    __syncthreads();
    if (h[tid] > 0) base[tid] = atomicAdd(&off[tid], h[tid]);
    __syncthreads();
    if (e < E) perm[base[k] + rank] = e;
}

// ---- MFMA corr: one wave per edge; B-frags hoisted; float2 epilogue ----
__global__ __launch_bounds__(64, 4) void corr_mfma(
        const uint4* __restrict__ fH,    // [N,16,H0,W0] uint4
        const uint4* __restrict__ f1H,   // [N,16,H1,W1] uint4
        const uint4* __restrict__ gH4,   // [M,9,16] uint4
        const float* __restrict__ coords,
        const int* __restrict__ ii,
        const int* __restrict__ jj,
        const int* __restrict__ perm,
        float* __restrict__ out) {
    __shared__ float sC[2 * NCELL * SCSTR];

    int nwg = gridDim.x;
    int q = nwg >> 3, r = nwg & 7;
    int xcd = blockIdx.x & 7;
    int ib = blockIdx.x >> 3;
    int orig = (xcd < r ? xcd * (q + 1) : r * (q + 1) + (xcd - r) * q) + ib;
    int e = perm ? perm[orig] : orig;

    int l = threadIdx.x;
    int lrow = l & 15;        // A row (cell-in-tile) / B col (pq)
    int lk = l >> 4;          // k-chunk 0..3 (8 channels each)

    int iie = __builtin_amdgcn_readfirstlane(ii[e]);
    int jje = __builtin_amdgcn_readfirstlane(jj[e]);
    const float* cb = coords + (size_t)e * 18;

    float cx = cb[0], cy = cb[1];
    int bx0 = (int)floorf(cx) - RADIUS;
    int by0 = (int)floorf(cy) - RADIUS;
    int bx1 = (int)floorf(cx * 0.25f) - RADIUS;
    int by1 = (int)floorf(cy * 0.25f) - RADIUS;

    // hoist all 4 B-fragments (16 VGPR)
    int pqc = min(lrow, 8);
    const uint4* gb = gH4 + (size_t)iie * 144 + pqc * 16 + lk;
    AB bfr[4];
#pragma unroll
    for (int kk = 0; kk < 4; ++kk) bfr[kk].u4 = gb[kk * 4];

    int off0[7], off1[7];
#pragma unroll
    for (int t = 0; t < 7; ++t) {
        int c = min(t * 16 + lrow, NCELL - 1);
        int iy = c / EXT, ix = c - iy * EXT;
        int gy0 = min(max(by0 + iy, 0), H0 - 1);
        int gx0 = min(max(bx0 + ix, 0), W0 - 1);
        int gy1 = min(max(by1 + iy, 0), H1 - 1);
        int gx1 = min(max(bx1 + ix, 0), W1 - 1);
        off0[t] = gy0 * W0 + gx0;
        off1[t] = gy1 * W1 + gx1;
    }

    const uint4* f0 = fH + (size_t)jje * NG * HW0;
    const uint4* f1 = f1H + (size_t)jje * NG * HW1;

    f32x4 acc0[7], acc1[7];
#pragma unroll
    for (int t = 0; t < 7; ++t) {
        acc0[t] = (f32x4){0.f, 0.f, 0.f, 0.f};
        acc1[t] = (f32x4){0.f, 0.f, 0.f, 0.f};
    }

#pragma unroll
    for (int kk = 0; kk < 4; ++kk) {
        const uint4* p0 = f0 + (size_t)(kk * 4 + lk) * HW0;
        const uint4* p1 = f1 + (size_t)(kk * 4 + lk) * HW1;
        AB a[7];
#pragma unroll
        for (int t = 0; t < 7; ++t) a[t].u4 = p0[off0[t]];
#pragma unroll
        for (int t = 0; t < 7; ++t)
            acc0[t] = __builtin_amdgcn_mfma_f32_16x16x32_f16(a[t].h8, bfr[kk].h8, acc0[t], 0, 0, 0);
#pragma unroll
        for (int t = 0; t < 7; ++t) a[t].u4 = p1[off1[t]];
#pragma unroll
        for (int t = 0; t < 7; ++t)
            acc1[t] = __builtin_amdgcn_mfma_f32_16x16x32_f16(a[t].h8, bfr[kk].h8, acc1[t], 0, 0, 0);
    }

    // C layout: col = l&15 (pq), row = (l>>4)*4 + reg (cell-in-tile)
    if (lrow < 9) {
#pragma unroll
        for (int t = 0; t < 7; ++t) {
#pragma unroll
            for (int r2 = 0; r2 < 4; ++r2) {
                int cell = t * 16 + lk * 4 + r2;
                if (cell < NCELL) {
                    sC[cell * SCSTR + lrow] = acc0[t][r2];
                    sC[NCELL * SCSTR + cell * SCSTR + lrow] = acc1[t][r2];
                }
            }
        }
    }
    __syncthreads();

    // float2 epilogue: rr = (a*7+b)*9 + pq, both levels at once, coalesced 8B stores
    float2* op = reinterpret_cast<float2*>(out + (size_t)e * 882);
#pragma unroll
    for (int w = 0; w < 7; ++w) {
        int rr = l + w * 64;
        if (rr < 441) {
            int pq = rr % 9;
            int ab = rr / 9;
            int a = ab / 7, b = ab - a * 7;
            float x0c = cb[pq * 2 + 0];
            float y0c = cb[pq * 2 + 1];
            float2 res;
#pragma unroll
            for (int lvl = 0; lvl < 2; ++lvl) {
                float s = lvl ? 0.25f : 1.f;
                float x = x0c * s;
                float y = y0c * s;
                float x0f = floorf(x), y0f = floorf(y);
                float fx = x - x0f, fy = y - y0f;
                int offx = (int)x0f - RADIUS - (lvl ? bx1 : bx0);
                int offy = (int)y0f - RADIUS - (lvl ? by1 : by0);
                int cell2 = (offy + a) * EXT + (offx + b);
                int base = lvl * (NCELL * SCSTR) + cell2 * SCSTR + pq;
                float c00 = sC[base];
                float c01 = sC[base + SCSTR];
                float c10 = sC[base + EXT * SCSTR];
                float c11 = sC[base + EXT * SCSTR + SCSTR];
                float v = (1.f - fy) * (1.f - fx) * c00 + (1.f - fy) * fx * c01
                        + fy * (1.f - fx) * c10 + fy * fx * c11;
                if (lvl) res.y = v; else res.x = v;
            }
            op[rr] = res;
        }
    }
}

// ---- fp32 fallback (small ws) ----
__global__ __launch_bounds__(256) void pool_fm1T(const float* __restrict__ fm0,
                                                 float* __restrict__ fm1T) {
    __shared__ float s[C_CH * 41];
    int blk = blockIdx.x;
    int yo = blk % H1;
    int n = blk / H1;
    for (int pair = threadIdx.x; pair < C_CH * W1; pair += 256) {
        int c = pair / W1, xo = pair - c * W1;
        const float* p = fm0 + (((size_t)(n * C_CH + c) * H0) + yo * 4) * W0 + xo * 4;
        float sum = 0.f;
#pragma unroll
        for (int yl = 0; yl < 4; ++yl) {
            float4 v = *reinterpret_cast<const float4*>(p + yl * W0);
            sum += v.x + v.y + v.z + v.w;
        }
        s[c * 41 + xo] = sum * (1.f / 16.f);
    }
    __syncthreads();
    float* dp = fm1T + (size_t)blk * W1 * C_CH;
    for (int t = threadIdx.x; t < W1 * C_CH; t += 256) {
        int xo = t >> 7, c = t & 127;
        dp[t] = s[c * 41 + xo];
    }
}

__global__ __launch_bounds__(128) void corr_kernel(
        const float* __restrict__ fmap, const float* __restrict__ fm1T,
        const float* __restrict__ gmap, const float* __restrict__ coords,
        const int* __restrict__ ii, const int* __restrict__ jj,
        float* __restrict__ out) {
    __shared__ float sC[2 * NCELL * SCSTR];
    int e = blockIdx.x;
    int tid = threadIdx.x;
    int iie = __builtin_amdgcn_readfirstlane(ii[e]);
    int jje = __builtin_amdgcn_readfirstlane(jj[e]);
    const float* cb = coords + (size_t)e * 18;
    float cx = cb[0], cy = cb[1];
    int bx0 = (int)floorf(cx) - RADIUS;
    int by0 = (int)floorf(cy) - RADIUS;
    int bx1 = (int)floorf(cx * 0.25f) - RADIUS;
    int by1 = (int)floorf(cy * 0.25f) - RADIUS;
    int cell = min(tid, NCELL - 1);
    int iy = cell / EXT, ix = cell - iy * EXT;
    int gy0 = min(max(by0 + iy, 0), H0 - 1);
    int gx0 = min(max(bx0 + ix, 0), W0 - 1);
    int gy1 = min(max(by1 + iy, 0), H1 - 1);
    int gx1 = min(max(bx1 + ix, 0), W1 - 1);
    const float* fp0 = fmap + (size_t)jje * C_CH * HW0 + gy0 * W0 + gx0;
    const float* fp1 = fm1T + (((size_t)jje * H1 + gy1) * W1 + gx1) * C_CH;
    float acc0[9], acc1[9];
#pragma unroll
    for (int pq = 0; pq < 9; ++pq) { acc0[pq] = 0.f; acc1[pq] = 0.f; }
    const float* gp = gmap + (size_t)iie * (C_CH * 9);
#pragma unroll 2
    for (int c = 0; c < C_CH; c += 4) {
        float f0 = fp0[(size_t)(c + 0) * HW0];
        float f1 = fp0[(size_t)(c + 1) * HW0];
        float f2 = fp0[(size_t)(c + 2) * HW0];
        float f3 = fp0[(size_t)(c + 3) * HW0];
        float4 fv = *reinterpret_cast<const float4*>(fp1 + c);
#pragma unroll
        for (int pq = 0; pq < 9; ++pq) {
            float g0 = gp[(c + 0) * 9 + pq];
            float g1 = gp[(c + 1) * 9 + pq];
            float g2 = gp[(c + 2) * 9 + pq];
            float g3 = gp[(c + 3) * 9 + pq];
            acc0[pq] += f0 * g0 + f1 * g1 + f2 * g2 + f3 * g3;
            acc1[pq] += fv.x * g0 + fv.y * g1 + fv.z * g2 + fv.w * g3;
        }
    }
    if (tid < NCELL) {
        float* s0 = &sC[cell * SCSTR];
        float* s1 = &sC[NCELL * SCSTR + cell * SCSTR];
        *reinterpret_cast<float4*>(s0)     = float4{acc0[0], acc0[1], acc0[2], acc0[3]};
        *reinterpret_cast<float4*>(s0 + 4) = float4{acc0[4], acc0[5], acc0[6], acc0[7]};
        s0[8] = acc0[8];
        *reinterpret_cast<float4*>(s1)     = float4{acc1[0], acc1[1], acc1[2], acc1[3]};
        *reinterpret_cast<float4*>(s1 + 4) = float4{acc1[4], acc1[5], acc1[6], acc1[7]};
        s1[8] = acc1[8];
    }
    __syncthreads();
    for (int o = tid; o < 882; o += 128) {
        int lvl = o & 1;
        int rr = o >> 1;
        int pq = rr % 9;
        int ab = rr / 9;
        int a = ab / 7, b = ab - a * 7;
        float s = lvl ? 0.25f : 1.f;
        float x = cb[pq * 2 + 0] * s;
        float y = cb[pq * 2 + 1] * s;
        float x0f = floorf(x), y0f = floorf(y);
        float fx = x - x0f, fy = y - y0f;
        int offx = (int)x0f - RADIUS - (lvl ? bx1 : bx0);
        int offy = (int)y0f - RADIUS - (lvl ? by1 : by0);
        int cell2 = (offy + a) * EXT + (offx + b);
        int base = lvl * (NCELL * SCSTR) + cell2 * SCSTR + pq;
        float c00 = sC[base];
        float c01 = sC[base + SCSTR];
        float c10 = sC[base + EXT * SCSTR];
        float c11 = sC[base + EXT * SCSTR + SCSTR];
        float v = (1.f - fy) * (1.f - fx) * c00 + (1.f - fy) * fx * c01
                + fy * (1.f - fx) * c10 + fy * fx * c11;
        out[(size_t)e * 882 + (size_t)rr * 2 + lvl] = v;
    }
}

extern "C" void kernel_launch(void* const* d_in, const int* in_sizes, int n_in,
                              void* d_out, int out_size, void* d_ws, size_t ws_size,
                              hipStream_t stream) {
    const float* fmap   = (const float*)d_in[0];
    const float* gmap   = (const float*)d_in[1];
    const float* coords = (const float*)d_in[2];
    const int* ii       = (const int*)d_in[3];
    const int* jj       = (const int*)d_in[4];
    float* out = (float*)d_out;
    int E = in_sizes[3];

    size_t szFH  = (size_t)N_FR * C_CH * HW0 * 2;       // 78.6 MB
    size_t szF1H = (size_t)N_FR * C_CH * HW1 * 2;       // 4.9 MB
    size_t szGH  = (size_t)M_PT * 9 * C_CH * 2 + 4096;  // 3.5 MB (+pad)
    size_t need_h = szFH + szF1H + szGH + 2048 + (size_t)E * 4;

    if (ws_size >= need_h) {
        uint4* fH  = (uint4*)d_ws;
        uint4* f1H = (uint4*)((char*)d_ws + szFH);
        unsigned* gH = (unsigned*)((char*)d_ws + szFH + szF1H);
        int* cnt  = (int*)((char*)d_ws + szFH + szF1H + szGH);
        int* off  = cnt + NBKT;
        int* perm = off + NBKT;

        pack_pool<<<N_FR * NG * H1, 256, 0, stream>>>(fmap, fH, f1H);
        gpack<<<M_PT, 128, 0, stream>>>(gmap, gH);

        hipMemsetAsync(cnt, 0, 2 * NBKT * sizeof(int), stream);
        int nb = (E + NBKT - 1) / NBKT;
        hist_kernel<<<nb, NBKT, 0, stream>>>(jj, coords, cnt, E);
        scan_kernel<<<1, 64, 0, stream>>>(cnt, off);
        scatter_kernel<<<nb, NBKT, 0, stream>>>(jj, coords, off, perm, E);

        corr_mfma<<<E, 64, 0, stream>>>(fH, f1H, (const uint4*)gH,
                                        coords, ii, jj, perm, out);
        return;
    }

    // ---- fp32 fallback ----
    float* fm1T = (float*)d_ws;
    pool_fm1T<<<N_FR * H1, 256, 0, stream>>>(fmap, fm1T);
    corr_kernel<<<E, 128, 0, stream>>>(fmap, fm1T, gmap, coords, ii, jj, out);
}